// Round 2
// baseline (2920.901 us; speedup 1.0000x reference)
//
#include <hip/hip_runtime.h>
#include <math.h>

// Round 4: R0 swapped structure + explicit register-bank software pipelining.
// R0 post-mortem: latency-bound (MfmaUtil 4.5%, VALU 17%, HBM 2.7%) — only
// ~4 x 16B loads in flight/wave (VGPR_Count 56, accs in AGPR). This round
// forces 18 weight loads in flight (depth-6 banks) in k_inv GEMM1, hoists
// GEMM2 weights behind the LN phase, and fully preloads k_mrg weights.

typedef short short8 __attribute__((ext_vector_type(8)));
typedef float f32x16 __attribute__((ext_vector_type(16)));

#define SFA 392   // k_inv feat row stride (ushorts); 784B = 196 dwords ≡ 4 mod 32
#define SFB 328   // k_mrg feat row stride (ushorts); 656B = 164 dwords ≡ 4 mod 32
#define ZST 129   // zbuf row stride (floats); ≡1 mod 32 -> conflict-free ds_add

__device__ __forceinline__ unsigned short f2bf(float x) {
  union { float f; unsigned u; } v; v.f = x;
  unsigned r = (v.u + 0x7FFFu + ((v.u >> 16) & 1u)) >> 16;
  return (unsigned short)r;
}
__device__ __forceinline__ float silu_f(float x) { return x / (1.0f + __expf(-x)); }
__device__ __forceinline__ unsigned cvtpk(float lo, float hi) {
  unsigned d;
  asm("v_cvt_pk_bf16_f32 %0, %1, %2" : "=v"(d) : "v"(lo), "v"(hi));
  return d;
}

__global__ void k_init(float* __restrict__ node_out, int n, int* __restrict__ last_idx) {
  int i = blockIdx.x * blockDim.x + threadIdx.x;
  if (i == 0) *last_idx = -1;
  for (; i < n; i += gridDim.x * blockDim.x) node_out[i] = 0.0f;
}

__global__ void k_mask(const int* __restrict__ src, const int* __restrict__ dst,
                       int E, unsigned char* __restrict__ rawmask, int* __restrict__ last_idx) {
  int i = blockIdx.x * blockDim.x + threadIdx.x;
  if (i >= E) return;
  int s0 = src[i], d0 = dst[i];
  int s1 = (i + 1 < E) ? src[i + 1] : 0;   // _shift pads 0
  int d1 = (i + 1 < E) ? dst[i + 1] : 0;
  int m = (s0 == s1) && (s0 != d0) && (s1 != d1);
  rawmask[i] = (unsigned char)m;
  if (m) atomicMax(last_idx, i);
}

// Wfa = iw1[:,320:]@aw2 ; cfa = iw1[:,320:]@ab2 ; angle closed-form LN folds.
__global__ void k_setup(const float* __restrict__ iw1, const float* __restrict__ aw2,
                        const float* __restrict__ ab2,
                        const float* __restrict__ aw1, const float* __restrict__ ab1,
                        const float* __restrict__ ag,
                        float* __restrict__ Wfa, float* __restrict__ cfa,
                        float* __restrict__ wg, float* __restrict__ bg,
                        float* __restrict__ angp) {
  int n = blockIdx.x * blockDim.x + threadIdx.x;
  if (n < 384 * 64) {
    int r = n >> 6, j = n & 63;
    float acc = 0.0f;
    for (int k = 0; k < 64; ++k) acc += iw1[r * 384 + 320 + k] * aw2[k * 64 + j];
    Wfa[n] = acc;
  } else if (n < 384 * 64 + 384) {
    int r = n - 384 * 64;
    float acc = 0.0f;
    for (int k = 0; k < 64; ++k) acc += iw1[r * 384 + 320 + k] * ab2[k];
    cfa[r] = acc;
  } else if (n < 384 * 64 + 384 + 64) {
    int j = n - (384 * 64 + 384);
    float wm = 0.f, bm = 0.f;
    for (int k = 0; k < 64; ++k) { wm += aw1[k]; bm += ab1[k]; }
    wm *= (1.f / 64.f); bm *= (1.f / 64.f);
    wg[j] = (aw1[j] - wm) * ag[j];
    bg[j] = (ab1[j] - bm) * ag[j];
    if (j == 0) {
      float vw = 0.f, cwb = 0.f, vb = 0.f;
      for (int k = 0; k < 64; ++k) {
        float dw = aw1[k] - wm, db = ab1[k] - bm;
        vw += dw * dw; cwb += dw * db; vb += db * db;
      }
      angp[0] = vw * (1.f / 64.f);
      angp[1] = cwb * (1.f / 64.f);
      angp[2] = vb * (1.f / 64.f);
    }
  }
}

// Swizzle weights into 32x32x16 A-fragment order:
// frag (nt,kt), lane l: value = W[n = nt*32 + (l&31)][k = kt*16 + ((l>>5)&1)*8 + j].
__global__ void k_swz(const float* __restrict__ iw1, const float* __restrict__ iw2,
                      const float* __restrict__ mw1, const float* __restrict__ mw2,
                      const float* __restrict__ Wfa,
                      unsigned short* __restrict__ B1, unsigned short* __restrict__ B2,
                      unsigned short* __restrict__ B3, unsigned short* __restrict__ B4) {
  const int NC1 = 12 * 24 * 64, NC2 = 4 * 24 * 64, NC3 = 4 * 20 * 64, NC4 = 4 * 8 * 64;
  int cid = blockIdx.x * blockDim.x + threadIdx.x;
  int region, rel, KT;
  unsigned short* out;
  if (cid < NC1)                        { region = 1; rel = cid;                   KT = 24; out = B1; }
  else if (cid < NC1 + NC2)             { region = 2; rel = cid - NC1;             KT = 24; out = B2; }
  else if (cid < NC1 + NC2 + NC3)       { region = 3; rel = cid - NC1 - NC2;       KT = 20; out = B3; }
  else if (cid < NC1 + NC2 + NC3 + NC4) { region = 4; rel = cid - NC1 - NC2 - NC3; KT = 8;  out = B4; }
  else return;
  int l = rel & 63;
  int ktn = rel >> 6;
  int kt = ktn % KT, nt = ktn / KT;
  int n = nt * 32 + (l & 31);
  int k0 = kt * 16 + ((l >> 5) & 1) * 8;
  short8 pk;
  #pragma unroll
  for (int j = 0; j < 8; ++j) {
    int k = k0 + j;
    float v;
    if (region == 1)      v = (k < 320) ? iw1[n * 384 + k] : Wfa[n * 64 + (k - 320)];
    else if (region == 2) v = iw2[n * 384 + k];
    else if (region == 3) v = mw1[n * 320 + k];
    else                  v = mw2[n * 128 + k];
    pk[j] = (short)f2bf(v);
  }
  *(short8*)(out + ((size_t)rel << 3)) = pk;
}

__global__ __launch_bounds__(256, 3)
void k_inv(const float* __restrict__ atom, const float* __restrict__ el,
           const float* __restrict__ ev,
           const int* __restrict__ src, const int* __restrict__ dst,
           const unsigned char* __restrict__ rawmask, const int* __restrict__ last_idx,
           const float* __restrict__ ib1, const float* __restrict__ ig,
           const float* __restrict__ ibn, const float* __restrict__ ib2,
           const float* __restrict__ cfa, const float* __restrict__ wg,
           const float* __restrict__ bg, const float* __restrict__ abn,
           const float* __restrict__ angp,
           const unsigned short* __restrict__ Bsw1, const unsigned short* __restrict__ Bsw2,
           float* __restrict__ node_out, int E) {
  __shared__ __attribute__((aligned(16))) unsigned short sf[32 * SFA];  // 25088 B; zbuf overlay
  __shared__ __attribute__((aligned(16))) float stab[1664];  // ib1|cfa|ig|ibn|ib2
  __shared__ float ssum[128], ssq[128], smean[32], srstd[32];
  __shared__ float scos[32], srr[32], smaskf[32];
  __shared__ int ssrc[32], sdst[32], sdsts[32];

  const int t = threadIdx.x;
  const int lane = t & 63;
  const int w = t >> 6;
  const int e31 = lane & 31;
  const int hi = lane >> 5;
  const int geb = blockIdx.x * 32;
  float* zbuf = (float*)sf;

  // ---- stage bias/LN tables ----
  for (int i = t; i < 1664; i += 256) {
    float v;
    if (i < 384) v = ib1[i];
    else if (i < 768) v = cfa[i - 384];
    else if (i < 1152) v = ig[i - 768];
    else if (i < 1536) v = ibn[i - 1152];
    else v = ib2[i - 1536];
    stab[i] = v;
  }

  // ---- pre-pass: per-edge mask, indices, cos, closed-form angle-LN rstd ----
  if (t < 32) {
    int e = t, ge = geb + e;
    int last = *last_idx;
    int m0 = 0, m1 = 0, s0 = 0, d0v = 0, d1v = 0;
    if (ge < E) { s0 = src[ge]; d0v = dst[ge]; m0 = rawmask[ge] && (ge != last); }
    if (ge + 1 < E) { d1v = dst[ge + 1]; m1 = rawmask[ge + 1] && (ge + 1 != last); }
    ssrc[e] = s0; sdst[e] = d0v; sdsts[e] = d1v;
    smaskf[e] = m0 ? 1.0f : 0.0f;
    float cosv = 0.f;
    if (m0 && m1) {
      float ax = ev[3 * ge], ay = ev[3 * ge + 1], az = ev[3 * ge + 2];
      float bx = ev[3 * ge + 3], by = ev[3 * ge + 4], bz = ev[3 * ge + 5];
      cosv = (ax * bx + ay * by + az * bz) *
             rsqrtf((ax * ax + ay * ay + az * az) * (bx * bx + by * by + bz * bz));
    }
    scos[e] = cosv;
    srr[e] = rsqrtf(cosv * cosv * angp[0] + 2.f * cosv * angp[1] + angp[2] + 1e-6f);
  }
  __syncthreads();

  // ---- stage feat [32][384] bf16 into LDS (mask-zeroed; angle cols closed-form) ----
  #pragma unroll
  for (int ii = 0; ii < 6; ++ii) {
    int cid = t + 256 * ii;          // 1536 chunks of 8
    int e = cid / 48, c0 = (cid % 48) * 8;
    int ge = geb + e;
    float mk = smaskf[e];
    float v[8];
    if (c0 < 320) {
      const float* sp;
      if (c0 < 64)        sp = atom + (size_t)ssrc[e] * 64 + c0;
      else if (c0 < 128)  sp = atom + (size_t)sdst[e] * 64 + (c0 - 64);
      else if (c0 < 192)  sp = el + (size_t)ge * 64 + (c0 - 128);
      else if (c0 < 256)  sp = atom + (size_t)sdsts[e] * 64 + (c0 - 192);
      else                sp = el + (size_t)(ge + 1) * 64 + (c0 - 256);
      bool ld = (ge < E) && (mk > 0.f) && !(c0 >= 256 && ge + 1 >= E);
      if (ld) {
        float4 p0 = *(const float4*)sp;
        float4 p1 = *(const float4*)(sp + 4);
        v[0] = p0.x; v[1] = p0.y; v[2] = p0.z; v[3] = p0.w;
        v[4] = p1.x; v[5] = p1.y; v[6] = p1.z; v[7] = p1.w;
      } else {
        #pragma unroll
        for (int j = 0; j < 8; ++j) v[j] = 0.f;
      }
    } else {
      int j0 = c0 - 320;
      float cosv = scos[e], rr = srr[e];
      float4 w0 = *(const float4*)(wg + j0),  w1 = *(const float4*)(wg + j0 + 4);
      float4 g0 = *(const float4*)(bg + j0),  g1 = *(const float4*)(bg + j0 + 4);
      float4 n0 = *(const float4*)(abn + j0), n1 = *(const float4*)(abn + j0 + 4);
      float W[8]  = {w0.x, w0.y, w0.z, w0.w, w1.x, w1.y, w1.z, w1.w};
      float G[8]  = {g0.x, g0.y, g0.z, g0.w, g1.x, g1.y, g1.z, g1.w};
      float Bn[8] = {n0.x, n0.y, n0.z, n0.w, n1.x, n1.y, n1.z, n1.w};
      #pragma unroll
      for (int j = 0; j < 8; ++j) {
        float hn = (cosv * W[j] + G[j]) * rr + Bn[j];
        v[j] = mk * silu_f(hn);
      }
    }
    short8 pk;
    #pragma unroll
    for (int j = 0; j < 8; ++j) pk[j] = (short)f2bf(v[j]);
    *(short8*)(sf + e * SFA + c0) = pk;
  }

  // ---- preload GEMM1 weight pipeline (issues before barrier: latency overlaps) ----
  const unsigned short* sfb = sf + e31 * SFA + hi * 8;
  const unsigned short* a0p = Bsw1 + ((((3 * w) * 24) * 64 + lane) << 3);
  short8 wl[6][3];
  #pragma unroll
  for (int p = 0; p < 6; ++p) {
    wl[p][0] = *(const short8*)(a0p + p * 512);
    wl[p][1] = *(const short8*)(a0p + 12288 + p * 512);
    wl[p][2] = *(const short8*)(a0p + 24576 + p * 512);
  }

  // ---- accumulator init: bias + mask*cfa ----
  const float maskv = smaskf[e31];
  f32x16 acc0, acc1, acc2;
  #pragma unroll
  for (int j = 0; j < 3; ++j) {
    const int nt = 3 * w + j;
    f32x16 a;
    #pragma unroll
    for (int rq = 0; rq < 4; ++rq) {
      const float4 bq = *(const float4*)(stab + nt * 32 + rq * 8 + hi * 4);
      const float4 cq = *(const float4*)(stab + 384 + nt * 32 + rq * 8 + hi * 4);
      a[rq * 4 + 0] = bq.x + maskv * cq.x;
      a[rq * 4 + 1] = bq.y + maskv * cq.y;
      a[rq * 4 + 2] = bq.z + maskv * cq.z;
      a[rq * 4 + 3] = bq.w + maskv * cq.w;
    }
    if (j == 0) acc0 = a; else if (j == 1) acc1 = a; else acc2 = a;
  }
  __syncthreads();

  // ---- GEMM1 (swapped): depth-6 weight banks, depth-3 LDS feat banks ----
  {
    short8 fl[3];
    #pragma unroll
    for (int p = 0; p < 3; ++p) fl[p] = *(const short8*)(sfb + p * 16);
    #pragma unroll
    for (int kt = 0; kt < 24; ++kt) {
      const int c6 = kt % 6, c3 = kt % 3;
      const short8 b = fl[c3];
      acc0 = __builtin_amdgcn_mfma_f32_32x32x16_bf16(wl[c6][0], b, acc0, 0, 0, 0);
      acc1 = __builtin_amdgcn_mfma_f32_32x32x16_bf16(wl[c6][1], b, acc1, 0, 0, 0);
      acc2 = __builtin_amdgcn_mfma_f32_32x32x16_bf16(wl[c6][2], b, acc2, 0, 0, 0);
      if (kt < 21) fl[c3] = *(const short8*)(sfb + (kt + 3) * 16);
      if (kt < 18) {
        wl[c6][0] = *(const short8*)(a0p + (kt + 6) * 512);
        wl[c6][1] = *(const short8*)(a0p + 12288 + (kt + 6) * 512);
        wl[c6][2] = *(const short8*)(a0p + 24576 + (kt + 6) * 512);
      }
    }
  }

  // ---- LN stats: per-lane sum over own 48 n-values + partner half + cross-wave ----
  {
    float s = 0.f, ss = 0.f;
    #pragma unroll
    for (int r = 0; r < 16; ++r) {
      s += acc0[r] + acc1[r] + acc2[r];
      ss += acc0[r] * acc0[r] + acc1[r] * acc1[r] + acc2[r] * acc2[r];
    }
    s += __shfl_xor(s, 32, 64);
    ss += __shfl_xor(ss, 32, 64);
    if (hi == 0) { ssum[w * 32 + e31] = s; ssq[w * 32 + e31] = ss; }
  }

  // ---- hoist GEMM2 weight loads: independent of stats/pack, cover their latency ----
  short8 wz[3][4];
  #pragma unroll
  for (int p = 0; p < 3; ++p) {
    const unsigned short* bp = Bsw2 + (((6 * w + p) * 64 + lane) << 3);
    wz[p][0] = *(const short8*)(bp);
    wz[p][1] = *(const short8*)(bp + 12288);
    wz[p][2] = *(const short8*)(bp + 24576);
    wz[p][3] = *(const short8*)(bp + 36864);
  }
  __syncthreads();
  if (t < 32) {
    float sm = ssum[t] + ssum[32 + t] + ssum[64 + t] + ssum[96 + t];
    float sq = ssq[t] + ssq[32 + t] + ssq[64 + t] + ssq[96 + t];
    float mean = sm * (1.f / 384.f);
    float var = sq * (1.f / 384.f) - mean * mean;
    smean[t] = mean; srstd[t] = rsqrtf(var + 1e-6f);
  }
  {  // zero zbuf (feat tile is dead; 32*ZST = 4128 floats)
    float4* zp = (float4*)zbuf;
    for (int i = t; i < 1032; i += 256) zp[i] = make_float4(0.f, 0.f, 0.f, 0.f);
  }
  __syncthreads();

  // ---- normalize+silu in-register, pack to GEMM2 B-frags via cvt_pk + permlane32_swap ----
  const float meanv = smean[e31], rstdv = srstd[e31];
  unsigned fr[6][4];
  #pragma unroll
  for (int j = 0; j < 3; ++j) {
    const int nt = 3 * w + j;
    f32x16 a = (j == 0) ? acc0 : (j == 1) ? acc1 : acc2;
    float f[16];
    #pragma unroll
    for (int rq = 0; rq < 4; ++rq) {
      const float4 gq = *(const float4*)(stab + 768 + nt * 32 + rq * 8 + hi * 4);
      const float4 bq = *(const float4*)(stab + 1152 + nt * 32 + rq * 8 + hi * 4);
      f[rq * 4 + 0] = silu_f((a[rq * 4 + 0] - meanv) * rstdv * gq.x + bq.x);
      f[rq * 4 + 1] = silu_f((a[rq * 4 + 1] - meanv) * rstdv * gq.y + bq.y);
      f[rq * 4 + 2] = silu_f((a[rq * 4 + 2] - meanv) * rstdv * gq.z + bq.z);
      f[rq * 4 + 3] = silu_f((a[rq * 4 + 3] - meanv) * rstdv * gq.w + bq.w);
    }
    unsigned P0 = cvtpk(f[0], f[1]),  P1 = cvtpk(f[2], f[3]);
    unsigned P2 = cvtpk(f[4], f[5]),  P3 = cvtpk(f[6], f[7]);
    unsigned P4 = cvtpk(f[8], f[9]),  P5 = cvtpk(f[10], f[11]);
    unsigned P6 = cvtpk(f[12], f[13]), P7 = cvtpk(f[14], f[15]);
    asm volatile("v_permlane32_swap_b32 %0, %1" : "+v"(P0), "+v"(P2));
    asm volatile("v_permlane32_swap_b32 %0, %1" : "+v"(P1), "+v"(P3));
    asm volatile("v_permlane32_swap_b32 %0, %1" : "+v"(P4), "+v"(P6));
    asm volatile("v_permlane32_swap_b32 %0, %1" : "+v"(P5), "+v"(P7));
    fr[2 * j][0] = P0; fr[2 * j][1] = P1; fr[2 * j][2] = P2; fr[2 * j][3] = P3;
    fr[2 * j + 1][0] = P4; fr[2 * j + 1][1] = P5; fr[2 * j + 1][2] = P6; fr[2 * j + 1][3] = P7;
  }

  // ---- GEMM2 split-K: wave w covers k = 96w..96w+95 ; weights via wz banks ----
  f32x16 z0, z1, z2, z3;
  #pragma unroll
  for (int r = 0; r < 16; ++r) { z0[r] = 0.f; z1[r] = 0.f; z2[r] = 0.f; z3[r] = 0.f; }
  #pragma unroll
  for (int jk = 0; jk < 6; ++jk) {
    const int cur = jk % 3;
    union { unsigned u[4]; short8 s; } uu;
    uu.u[0] = fr[jk][0]; uu.u[1] = fr[jk][1]; uu.u[2] = fr[jk][2]; uu.u[3] = fr[jk][3];
    const short8 bop = uu.s;
    z0 = __builtin_amdgcn_mfma_f32_32x32x16_bf16(wz[cur][0], bop, z0, 0, 0, 0);
    z1 = __builtin_amdgcn_mfma_f32_32x32x16_bf16(wz[cur][1], bop, z1, 0, 0, 0);
    z2 = __builtin_amdgcn_mfma_f32_32x32x16_bf16(wz[cur][2], bop, z2, 0, 0, 0);
    z3 = __builtin_amdgcn_mfma_f32_32x32x16_bf16(wz[cur][3], bop, z3, 0, 0, 0);
    if (jk < 3) {
      const unsigned short* bp = Bsw2 + (((6 * w + jk + 3) * 64 + lane) << 3);
      wz[cur][0] = *(const short8*)(bp);
      wz[cur][1] = *(const short8*)(bp + 12288);
      wz[cur][2] = *(const short8*)(bp + 24576);
      wz[cur][3] = *(const short8*)(bp + 36864);
    }
  }
  #pragma unroll
  for (int r = 0; r < 16; ++r) {
    const int zz = (r & 3) + 8 * (r >> 2) + 4 * hi;
    atomicAdd(zbuf + e31 * ZST + zz, z0[r]);
    atomicAdd(zbuf + e31 * ZST + 32 + zz, z1[r]);
    atomicAdd(zbuf + e31 * ZST + 64 + zz, z2[r]);
    atomicAdd(zbuf + e31 * ZST + 96 + zz, z3[r]);
  }
  __syncthreads();

  // ---- scatter to node_out ----
  for (int i = t; i < 4096; i += 256) {
    const int e = i >> 7, zz = i & 127;
    const int ge = geb + e;
    if (ge < E)
      atomicAdd(node_out + (size_t)sdst[e] * 128 + zz, zbuf[e * ZST + zz] + stab[1536 + zz]);
  }
}

__global__ __launch_bounds__(256, 3)
void k_mrg(const float* __restrict__ node, const float* __restrict__ el,
           const int* __restrict__ src, const int* __restrict__ dst,
           const float* __restrict__ mb1, const float* __restrict__ mg,
           const float* __restrict__ mbn, const float* __restrict__ mb2,
           const unsigned short* __restrict__ Bsw3, const unsigned short* __restrict__ Bsw4,
           float* __restrict__ edge_out, int E) {
  __shared__ __attribute__((aligned(16))) unsigned short sf[32 * SFB];  // 20992 B; zbuf overlay
  __shared__ __attribute__((aligned(16))) float stab[512];  // mb1|mg|mbn|mb2
  __shared__ float ssum[128], ssq[128], smean[32], srstd[32];
  __shared__ int ssrc[32], sdst[32];

  const int t = threadIdx.x;
  const int lane = t & 63;
  const int w = t >> 6;
  const int e31 = lane & 31;
  const int hi = lane >> 5;
  const int geb = blockIdx.x * 32;
  float* zbuf = (float*)sf;

  for (int i = t; i < 512; i += 256) {
    float v;
    if (i < 128) v = mb1[i];
    else if (i < 256) v = mg[i - 128];
    else if (i < 384) v = mbn[i - 256];
    else v = mb2[i - 384];
    stab[i] = v;
  }
  if (t < 32) {
    int ge = geb + t;
    int ok = ge < E;
    ssrc[t] = ok ? src[ge] : 0;
    sdst[t] = ok ? dst[ge] : 0;
  }
  __syncthreads();

  // ---- stage [32][320]: node[src] | node[dst] | el ----
  #pragma unroll
  for (int ii = 0; ii < 5; ++ii) {
    int cid = t + 256 * ii;          // 1280 chunks
    int e = cid / 40, c0 = (cid % 40) * 8;
    int ge = geb + e;
    float v[8];
    const float* sp;
    if (c0 < 128)       sp = node + (size_t)ssrc[e] * 128 + c0;
    else if (c0 < 256)  sp = node + (size_t)sdst[e] * 128 + (c0 - 128);
    else                sp = el + (size_t)ge * 64 + (c0 - 256);
    if (ge < E) {
      float4 p0 = *(const float4*)sp;
      float4 p1 = *(const float4*)(sp + 4);
      v[0] = p0.x; v[1] = p0.y; v[2] = p0.z; v[3] = p0.w;
      v[4] = p1.x; v[5] = p1.y; v[6] = p1.z; v[7] = p1.w;
    } else {
      #pragma unroll
      for (int j = 0; j < 8; ++j) v[j] = 0.f;
    }
    short8 pk;
    #pragma unroll
    for (int j = 0; j < 8; ++j) pk[j] = (short)f2bf(v[j]);
    *(short8*)(sf + e * SFB + c0) = pk;
  }

  // ---- preload ALL GEMM1 weights (80 VGPR) before the barrier ----
  const unsigned short* ap = Bsw3 + (((w * 20) * 64 + lane) << 3);
  short8 wl[20];
  #pragma unroll
  for (int p = 0; p < 20; ++p) wl[p] = *(const short8*)(ap + p * 512);

  f32x16 acc;
  #pragma unroll
  for (int rq = 0; rq < 4; ++rq) {
    const float4 bq = *(const float4*)(stab + w * 32 + rq * 8 + hi * 4);
    acc[rq * 4 + 0] = bq.x; acc[rq * 4 + 1] = bq.y;
    acc[rq * 4 + 2] = bq.z; acc[rq * 4 + 3] = bq.w;
  }
  __syncthreads();

  // ---- GEMM1 (swapped): wave w owns nt = w, K = 320; pure ds_read + MFMA ----
  {
    const unsigned short* sfb = sf + e31 * SFB + hi * 8;
    short8 fl[4];
    #pragma unroll
    for (int p = 0; p < 4; ++p) fl[p] = *(const short8*)(sfb + p * 16);
    #pragma unroll
    for (int kt = 0; kt < 20; ++kt) {
      const int c4 = kt & 3;
      acc = __builtin_amdgcn_mfma_f32_32x32x16_bf16(wl[kt], fl[c4], acc, 0, 0, 0);
      if (kt < 16) fl[c4] = *(const short8*)(sfb + (kt + 4) * 16);
    }
  }

  {
    float s = 0.f, ss = 0.f;
    #pragma unroll
    for (int r = 0; r < 16; ++r) { s += acc[r]; ss += acc[r] * acc[r]; }
    s += __shfl_xor(s, 32, 64);
    ss += __shfl_xor(ss, 32, 64);
    if (hi == 0) { ssum[w * 32 + e31] = s; ssq[w * 32 + e31] = ss; }
  }

  // ---- hoist GEMM2 weights (8 frags) behind stats/pack ----
  short8 wz[2][4];
  #pragma unroll
  for (int p = 0; p < 2; ++p) {
    const unsigned short* bp = Bsw4 + (((2 * w + p) * 64 + lane) << 3);
    wz[p][0] = *(const short8*)(bp);
    wz[p][1] = *(const short8*)(bp + 4096);
    wz[p][2] = *(const short8*)(bp + 8192);
    wz[p][3] = *(const short8*)(bp + 12288);
  }
  __syncthreads();
  if (t < 32) {
    float sm = ssum[t] + ssum[32 + t] + ssum[64 + t] + ssum[96 + t];
    float sq = ssq[t] + ssq[32 + t] + ssq[64 + t] + ssq[96 + t];
    float mean = sm * (1.f / 128.f);
    float var = sq * (1.f / 128.f) - mean * mean;
    smean[t] = mean; srstd[t] = rsqrtf(var + 1e-6f);
  }
  {
    float4* zp = (float4*)zbuf;
    for (int i = t; i < 1032; i += 256) zp[i] = make_float4(0.f, 0.f, 0.f, 0.f);
  }
  __syncthreads();

  const float meanv = smean[e31], rstdv = srstd[e31];
  unsigned fr[2][4];
  {
    float f[16];
    #pragma unroll
    for (int rq = 0; rq < 4; ++rq) {
      const float4 gq = *(const float4*)(stab + 128 + w * 32 + rq * 8 + hi * 4);
      const float4 bq = *(const float4*)(stab + 256 + w * 32 + rq * 8 + hi * 4);
      f[rq * 4 + 0] = silu_f((acc[rq * 4 + 0] - meanv) * rstdv * gq.x + bq.x);
      f[rq * 4 + 1] = silu_f((acc[rq * 4 + 1] - meanv) * rstdv * gq.y + bq.y);
      f[rq * 4 + 2] = silu_f((acc[rq * 4 + 2] - meanv) * rstdv * gq.z + bq.z);
      f[rq * 4 + 3] = silu_f((acc[rq * 4 + 3] - meanv) * rstdv * gq.w + bq.w);
    }
    unsigned P0 = cvtpk(f[0], f[1]),  P1 = cvtpk(f[2], f[3]);
    unsigned P2 = cvtpk(f[4], f[5]),  P3 = cvtpk(f[6], f[7]);
    unsigned P4 = cvtpk(f[8], f[9]),  P5 = cvtpk(f[10], f[11]);
    unsigned P6 = cvtpk(f[12], f[13]), P7 = cvtpk(f[14], f[15]);
    asm volatile("v_permlane32_swap_b32 %0, %1" : "+v"(P0), "+v"(P2));
    asm volatile("v_permlane32_swap_b32 %0, %1" : "+v"(P1), "+v"(P3));
    asm volatile("v_permlane32_swap_b32 %0, %1" : "+v"(P4), "+v"(P6));
    asm volatile("v_permlane32_swap_b32 %0, %1" : "+v"(P5), "+v"(P7));
    fr[0][0] = P0; fr[0][1] = P1; fr[0][2] = P2; fr[0][3] = P3;
    fr[1][0] = P4; fr[1][1] = P5; fr[1][2] = P6; fr[1][3] = P7;
  }

  // ---- GEMM2 split-K: wave w covers k = 32w..32w+31 ----
  f32x16 z0, z1, z2, z3;
  #pragma unroll
  for (int r = 0; r < 16; ++r) { z0[r] = 0.f; z1[r] = 0.f; z2[r] = 0.f; z3[r] = 0.f; }
  #pragma unroll
  for (int jk = 0; jk < 2; ++jk) {
    union { unsigned u[4]; short8 s; } uu;
    uu.u[0] = fr[jk][0]; uu.u[1] = fr[jk][1]; uu.u[2] = fr[jk][2]; uu.u[3] = fr[jk][3];
    const short8 bop = uu.s;
    z0 = __builtin_amdgcn_mfma_f32_32x32x16_bf16(wz[jk][0], bop, z0, 0, 0, 0);
    z1 = __builtin_amdgcn_mfma_f32_32x32x16_bf16(wz[jk][1], bop, z1, 0, 0, 0);
    z2 = __builtin_amdgcn_mfma_f32_32x32x16_bf16(wz[jk][2], bop, z2, 0, 0, 0);
    z3 = __builtin_amdgcn_mfma_f32_32x32x16_bf16(wz[jk][3], bop, z3, 0, 0, 0);
  }
  #pragma unroll
  for (int r = 0; r < 16; ++r) {
    const int zz = (r & 3) + 8 * (r >> 2) + 4 * hi;
    atomicAdd(zbuf + e31 * ZST + zz, z0[r]);
    atomicAdd(zbuf + e31 * ZST + 32 + zz, z1[r]);
    atomicAdd(zbuf + e31 * ZST + 64 + zz, z2[r]);
    atomicAdd(zbuf + e31 * ZST + 96 + zz, z3[r]);
  }
  __syncthreads();

  for (int i = t; i < 4096; i += 256) {
    const int e = i >> 7, zz = i & 127;
    const int ge = geb + e;
    if (ge < E) edge_out[(size_t)ge * 128 + zz] = zbuf[e * ZST + zz] + stab[384 + zz];
  }
}

extern "C" void kernel_launch(void* const* d_in, const int* in_sizes, int n_in,
                              void* d_out, int out_size, void* d_ws, size_t ws_size,
                              hipStream_t stream) {
  const float* atom = (const float*)d_in[0];
  const float* el   = (const float*)d_in[1];
  const float* ev   = (const float*)d_in[2];
  const int*   eidx = (const int*)d_in[3];
  const float* aw1  = (const float*)d_in[4];
  const float* ab1  = (const float*)d_in[5];
  const float* ag   = (const float*)d_in[6];
  const float* abn  = (const float*)d_in[7];
  const float* aw2  = (const float*)d_in[8];
  const float* ab2  = (const float*)d_in[9];
  const float* iw1  = (const float*)d_in[10];
  const float* ib1  = (const float*)d_in[11];
  const float* ig   = (const float*)d_in[12];
  const float* ibn  = (const float*)d_in[13];
  const float* iw2  = (const float*)d_in[14];
  const float* ib2  = (const float*)d_in[15];
  const float* mw1  = (const float*)d_in[16];
  const float* mb1  = (const float*)d_in[17];
  const float* mg   = (const float*)d_in[18];
  const float* mbn  = (const float*)d_in[19];
  const float* mw2  = (const float*)d_in[20];
  const float* mb2  = (const float*)d_in[21];

  const int N = in_sizes[0] / 64;
  const int E = in_sizes[1] / 64;
  const int* src = eidx;
  const int* dst = eidx + E;

  char* ws = (char*)d_ws;
  size_t off = 0;
  int* last_idx = (int*)(ws + off);          off += 256;
  unsigned char* rawmask = (unsigned char*)(ws + off); off += ((size_t)E + 255) & ~(size_t)255;
  float* Wfa  = (float*)(ws + off);          off += (size_t)384 * 64 * 4;
  float* cfa  = (float*)(ws + off);          off += 384 * 4;
  float* wg   = (float*)(ws + off);          off += 256;
  float* bg   = (float*)(ws + off);          off += 256;
  float* angp = (float*)(ws + off);          off += 256;
  unsigned short* B1 = (unsigned short*)(ws + off); off += (size_t)12 * 24 * 64 * 8 * 2;
  unsigned short* B2 = (unsigned short*)(ws + off); off += (size_t)4 * 24 * 64 * 8 * 2;
  unsigned short* B3 = (unsigned short*)(ws + off); off += (size_t)4 * 20 * 64 * 8 * 2;
  unsigned short* B4 = (unsigned short*)(ws + off); off += (size_t)4 * 8 * 64 * 8 * 2;

  float* node_out = (float*)d_out;
  float* edge_out = node_out + (size_t)N * 128;

  const int eb = (E + 255) / 256;
  const int tb = (E + 31) / 32;
  const int swz_n = 12 * 24 * 64 + 4 * 24 * 64 + 4 * 20 * 64 + 4 * 8 * 64;

  k_init<<<2048, 256, 0, stream>>>(node_out, N * 128, last_idx);
  k_mask<<<eb, 256, 0, stream>>>(src, dst, E, rawmask, last_idx);
  k_setup<<<(384 * 64 + 384 + 64 + 255) / 256, 256, 0, stream>>>(
      iw1, aw2, ab2, aw1, ab1, ag, Wfa, cfa, wg, bg, angp);
  k_swz<<<(swz_n + 255) / 256, 256, 0, stream>>>(iw1, iw2, mw1, mw2, Wfa, B1, B2, B3, B4);
  k_inv<<<tb, 256, 0, stream>>>(atom, el, ev, src, dst, rawmask, last_idx,
                                ib1, ig, ibn, ib2, cfa, wg, bg, abn, angp,
                                B1, B2, node_out, E);
  k_mrg<<<tb, 256, 0, stream>>>(node_out, el, src, dst,
                                mb1, mg, mbn, mb2, B3, B4, edge_out, E);
}

// Round 3
// 1176.483 us; speedup vs baseline: 2.4827x; 2.4827x over previous
//
#include <hip/hip_runtime.h>
#include <math.h>

// Round 5: revert to the verified 1149.7µs structure (64 edges/block, 4 waves
// x 16-edge m-tile, 16x16x32 MFMA, all waves share the B-weight stream ->
// L1 broadcast), plus ONE change: depth-1 double-buffered B-fragment loads
// (bfA/bfB banks, next-nt loads issued under current-nt MFMAs).
// k_inv gets __launch_bounds__(256,2) so the second bank fits in VGPRs
// (R1 lesson: (256,3)'s ~170-reg cap silently collapses the pipeline).

typedef short short8 __attribute__((ext_vector_type(8)));
typedef float f32x4 __attribute__((ext_vector_type(4)));

#define SFA 392   // k_inv feat row stride (ushorts); 784B -> 196 dwords, 196%32=4 -> 2-way
#define SFB 328   // k_mrg feat row stride (ushorts); 656B -> 164 dwords, 164%32=4 -> 2-way

__device__ __forceinline__ unsigned short f2bf(float x) {
  union { float f; unsigned u; } v; v.f = x;
  unsigned r = (v.u + 0x7FFFu + ((v.u >> 16) & 1u)) >> 16;
  return (unsigned short)r;
}
__device__ __forceinline__ float bf2f(unsigned short h) {
  union { unsigned u; float f; } v; v.u = ((unsigned)h) << 16;
  return v.f;
}
__device__ __forceinline__ float silu_f(float x) { return x / (1.0f + __expf(-x)); }

__global__ void k_init(float* __restrict__ node_out, int n, int* __restrict__ last_idx) {
  int i = blockIdx.x * blockDim.x + threadIdx.x;
  if (i == 0) *last_idx = -1;
  for (; i < n; i += gridDim.x * blockDim.x) node_out[i] = 0.0f;
}

__global__ void k_mask(const int* __restrict__ src, const int* __restrict__ dst,
                       int E, unsigned char* __restrict__ rawmask, int* __restrict__ last_idx) {
  int i = blockIdx.x * blockDim.x + threadIdx.x;
  if (i >= E) return;
  int s0 = src[i], d0 = dst[i];
  int s1 = (i + 1 < E) ? src[i + 1] : 0;   // _shift pads 0
  int d1 = (i + 1 < E) ? dst[i + 1] : 0;
  int m = (s0 == s1) && (s0 != d0) && (s1 != d1);
  rawmask[i] = (unsigned char)m;
  if (m) atomicMax(last_idx, i);
}

// Wfa = iw1[:,320:]@aw2 ; cfa = iw1[:,320:]@ab2 ; angle closed-form LN folds.
__global__ void k_setup(const float* __restrict__ iw1, const float* __restrict__ aw2,
                        const float* __restrict__ ab2,
                        const float* __restrict__ aw1, const float* __restrict__ ab1,
                        const float* __restrict__ ag,
                        float* __restrict__ Wfa, float* __restrict__ cfa,
                        float* __restrict__ wg, float* __restrict__ bg,
                        float* __restrict__ angp) {
  int n = blockIdx.x * blockDim.x + threadIdx.x;
  if (n < 384 * 64) {
    int r = n >> 6, j = n & 63;
    float acc = 0.0f;
    for (int k = 0; k < 64; ++k) acc += iw1[r * 384 + 320 + k] * aw2[k * 64 + j];
    Wfa[n] = acc;
  } else if (n < 384 * 64 + 384) {
    int r = n - 384 * 64;
    float acc = 0.0f;
    for (int k = 0; k < 64; ++k) acc += iw1[r * 384 + 320 + k] * ab2[k];
    cfa[r] = acc;
  } else if (n < 384 * 64 + 384 + 64) {
    int j = n - (384 * 64 + 384);
    float wm = 0.f, bm = 0.f;
    for (int k = 0; k < 64; ++k) { wm += aw1[k]; bm += ab1[k]; }
    wm *= (1.f / 64.f); bm *= (1.f / 64.f);
    wg[j] = (aw1[j] - wm) * ag[j];
    bg[j] = (ab1[j] - bm) * ag[j];
    if (j == 0) {
      float vw = 0.f, cwb = 0.f, vb = 0.f;
      for (int k = 0; k < 64; ++k) {
        float dw = aw1[k] - wm, db = ab1[k] - bm;
        vw += dw * dw; cwb += dw * db; vb += db * db;
      }
      angp[0] = vw * (1.f / 64.f);
      angp[1] = cwb * (1.f / 64.f);
      angp[2] = vb * (1.f / 64.f);
    }
  }
}

// Swizzle weights into B-fragment order: B[(nt*KT+kt)*64 + lane][8] with
// value = W[n = nt*16 + (lane&15)][k = kt*32 + ((lane>>4)&3)*8 + j]  (bf16).
__global__ void k_swz(const float* __restrict__ iw1, const float* __restrict__ iw2,
                      const float* __restrict__ mw1, const float* __restrict__ mw2,
                      const float* __restrict__ Wfa,
                      unsigned short* __restrict__ B1, unsigned short* __restrict__ B2,
                      unsigned short* __restrict__ B3, unsigned short* __restrict__ B4) {
  const int NC1 = 24 * 12 * 64, NC2 = 8 * 12 * 64, NC3 = 8 * 10 * 64, NC4 = 8 * 4 * 64;
  int cid = blockIdx.x * blockDim.x + threadIdx.x;
  int region, rel, KT;
  unsigned short* out;
  if (cid < NC1)                    { region = 1; rel = cid;                KT = 12; out = B1; }
  else if (cid < NC1 + NC2)         { region = 2; rel = cid - NC1;          KT = 12; out = B2; }
  else if (cid < NC1 + NC2 + NC3)   { region = 3; rel = cid - NC1 - NC2;    KT = 10; out = B3; }
  else if (cid < NC1 + NC2 + NC3 + NC4) { region = 4; rel = cid - NC1 - NC2 - NC3; KT = 4; out = B4; }
  else return;
  int l = rel & 63;
  int ktn = rel >> 6;
  int kt = ktn % KT, nt = ktn / KT;
  int n = nt * 16 + (l & 15);
  int k0 = kt * 32 + ((l >> 4) & 3) * 8;
  short8 pk;
  #pragma unroll
  for (int j = 0; j < 8; ++j) {
    int k = k0 + j;
    float v;
    if (region == 1)      v = (k < 320) ? iw1[n * 384 + k] : Wfa[n * 64 + (k - 320)];
    else if (region == 2) v = iw2[n * 384 + k];
    else if (region == 3) v = mw1[n * 320 + k];
    else                  v = mw2[n * 128 + k];
    pk[j] = (short)f2bf(v);
  }
  *(short8*)(out + ((size_t)rel << 3)) = pk;
}

__global__ __launch_bounds__(256, 2)
void k_inv(const float* __restrict__ atom, const float* __restrict__ el,
           const float* __restrict__ ev,
           const int* __restrict__ src, const int* __restrict__ dst,
           const unsigned char* __restrict__ rawmask, const int* __restrict__ last_idx,
           const float* __restrict__ ib1, const float* __restrict__ ig,
           const float* __restrict__ ibn, const float* __restrict__ ib2,
           const float* __restrict__ cfa, const float* __restrict__ wg,
           const float* __restrict__ bg, const float* __restrict__ abn,
           const float* __restrict__ angp,
           const unsigned short* __restrict__ Bsw1, const unsigned short* __restrict__ Bsw2,
           float* __restrict__ node_out, int E) {
  __shared__ __attribute__((aligned(16))) unsigned short sf[64 * SFA];  // 50176 B
  __shared__ float scos[64], srr[64], smaskf[64], smean[64], srstd[64];
  __shared__ int ssrc[64], sdst[64], sdsts[64];

  const int t = threadIdx.x;
  const int lane = t & 63;
  const int q = (lane >> 4) & 3;
  const int col = lane & 15;
  const int mbase = (t >> 6) * 16;
  const int geb = blockIdx.x * 64;

  // ---- pre-pass: per-edge mask, indices, cos, closed-form LN rstd ----
  if (t < 64) {
    int e = t, ge = geb + e;
    int last = *last_idx;
    int ok = ge < E;
    int m0 = 0, m1 = 0, s0 = 0, d0 = 0, d1 = 0;
    if (ok) { s0 = src[ge]; d0 = dst[ge]; m0 = rawmask[ge] && (ge != last); }
    if (ge + 1 < E) { d1 = dst[ge + 1]; m1 = rawmask[ge + 1] && (ge + 1 != last); }
    ssrc[e] = s0; sdst[e] = d0; sdsts[e] = d1;
    smaskf[e] = m0 ? 1.0f : 0.0f;
    float cosv = 0.f;
    if (m0 && m1) {
      float ax = ev[3 * ge], ay = ev[3 * ge + 1], az = ev[3 * ge + 2];
      float bx = ev[3 * ge + 3], by = ev[3 * ge + 4], bz = ev[3 * ge + 5];
      cosv = (ax * bx + ay * by + az * bz) *
             rsqrtf((ax * ax + ay * ay + az * az) * (bx * bx + by * by + bz * bz));
    }
    scos[e] = cosv;
    srr[e] = rsqrtf(cosv * cosv * angp[0] + 2.f * cosv * angp[1] + angp[2] + 1e-6f);
  }
  __syncthreads();

  // ---- stage feat [64][384] bf16 into LDS (mask-zeroed; angle cols closed-form) ----
  #pragma unroll
  for (int ii = 0; ii < 12; ++ii) {
    int cid = t + 256 * ii;          // 3072 chunks of 8
    int e = cid / 48, c0 = (cid % 48) * 8;
    int ge = geb + e;
    float mk = smaskf[e];
    float v[8];
    if (c0 < 320) {
      const float* sp;
      if (c0 < 64)        sp = atom + (size_t)ssrc[e] * 64 + c0;
      else if (c0 < 128)  sp = atom + (size_t)sdst[e] * 64 + (c0 - 64);
      else if (c0 < 192)  sp = el + (size_t)ge * 64 + (c0 - 128);
      else if (c0 < 256)  sp = atom + (size_t)sdsts[e] * 64 + (c0 - 192);
      else                sp = el + (size_t)(ge + 1) * 64 + (c0 - 256);
      bool ld = (ge < E) && (mk > 0.f) && !(c0 >= 256 && ge + 1 >= E);
      if (ld) {
        float4 p0 = *(const float4*)sp;
        float4 p1 = *(const float4*)(sp + 4);
        v[0] = p0.x; v[1] = p0.y; v[2] = p0.z; v[3] = p0.w;
        v[4] = p1.x; v[5] = p1.y; v[6] = p1.z; v[7] = p1.w;
      } else {
        #pragma unroll
        for (int j = 0; j < 8; ++j) v[j] = 0.f;
      }
    } else {
      int j0 = c0 - 320;
      float cosv = scos[e], rr = srr[e];
      float4 w0 = *(const float4*)(wg + j0),  w1 = *(const float4*)(wg + j0 + 4);
      float4 g0 = *(const float4*)(bg + j0),  g1 = *(const float4*)(bg + j0 + 4);
      float4 n0 = *(const float4*)(abn + j0), n1 = *(const float4*)(abn + j0 + 4);
      float W[8]  = {w0.x, w0.y, w0.z, w0.w, w1.x, w1.y, w1.z, w1.w};
      float G[8]  = {g0.x, g0.y, g0.z, g0.w, g1.x, g1.y, g1.z, g1.w};
      float Bn[8] = {n0.x, n0.y, n0.z, n0.w, n1.x, n1.y, n1.z, n1.w};
      #pragma unroll
      for (int j = 0; j < 8; ++j) {
        float hn = (cosv * W[j] + G[j]) * rr + Bn[j];
        v[j] = mk * silu_f(hn);
      }
    }
    short8 pk;
    #pragma unroll
    for (int j = 0; j < 8; ++j) pk[j] = (short)f2bf(v[j]);
    *(short8*)(sf + e * SFA + c0) = pk;
  }
  __syncthreads();

  // ---- GEMM1: H[16x384] = feat @ W1eff^T, per wave; double-buffered B stream ----
  short8 af[12];
  #pragma unroll
  for (int kt = 0; kt < 12; ++kt)
    af[kt] = *(const short8*)(sf + (mbase + col) * SFA + kt * 32 + q * 8);

  float mrow[4]; int drow[4];
  #pragma unroll
  for (int r = 0; r < 4; ++r) {
    int e = mbase + q * 4 + r;
    mrow[r] = smaskf[e];
    drow[r] = sdst[e];
  }

  float sums[4] = {0, 0, 0, 0}, sqs[4] = {0, 0, 0, 0};
  {
    short8 bfA[12], bfB[12];
    #pragma unroll
    for (int kt = 0; kt < 12; ++kt)
      bfA[kt] = *(const short8*)(Bsw1 + (((0 * 12 + kt) * 64 + lane) << 3));
    #pragma unroll 1
    for (int ntp = 0; ntp < 12; ++ntp) {
      const int nt0 = 2 * ntp, nt1 = nt0 + 1;
      const bool pf = (ntp < 11);
      {  // nt0: consume bfA, prefetch nt1 -> bfB
        int n = nt0 * 16 + col;
        float biasv = ib1[n], cfav = cfa[n];
        f32x4 acc;
        #pragma unroll
        for (int r = 0; r < 4; ++r) acc[r] = biasv + mrow[r] * cfav;
        #pragma unroll
        for (int kt = 0; kt < 12; ++kt) {
          bfB[kt] = *(const short8*)(Bsw1 + (((nt1 * 12 + kt) * 64 + lane) << 3));
          acc = __builtin_amdgcn_mfma_f32_16x16x32_bf16(af[kt], bfA[kt], acc, 0, 0, 0);
        }
        #pragma unroll
        for (int r = 0; r < 4; ++r) {
          float vv = acc[r];
          sums[r] += vv; sqs[r] += vv * vv;
          sf[(mbase + q * 4 + r) * SFA + nt0 * 16 + col] = f2bf(vv);
        }
      }
      {  // nt1: consume bfB, prefetch nt0+2 -> bfA
        int n = nt1 * 16 + col;
        float biasv = ib1[n], cfav = cfa[n];
        f32x4 acc;
        #pragma unroll
        for (int r = 0; r < 4; ++r) acc[r] = biasv + mrow[r] * cfav;
        #pragma unroll
        for (int kt = 0; kt < 12; ++kt) {
          if (pf)
            bfA[kt] = *(const short8*)(Bsw1 + ((((nt0 + 2) * 12 + kt) * 64 + lane) << 3));
          acc = __builtin_amdgcn_mfma_f32_16x16x32_bf16(af[kt], bfB[kt], acc, 0, 0, 0);
        }
        #pragma unroll
        for (int r = 0; r < 4; ++r) {
          float vv = acc[r];
          sums[r] += vv; sqs[r] += vv * vv;
          sf[(mbase + q * 4 + r) * SFA + nt1 * 16 + col] = f2bf(vv);
        }
      }
    }
  }

  // intra-quad (16-lane) reduction for per-edge LN stats
  #pragma unroll
  for (int r = 0; r < 4; ++r) {
    float s = sums[r], ss = sqs[r];
    for (int m = 1; m < 16; m <<= 1) { s += __shfl_xor(s, m, 64); ss += __shfl_xor(ss, m, 64); }
    sums[r] = s; sqs[r] = ss;
  }
  if (col == 0) {
    #pragma unroll
    for (int r = 0; r < 4; ++r) {
      float mean = sums[r] * (1.f / 384.f);
      float var = sqs[r] * (1.f / 384.f) - mean * mean;
      smean[mbase + q * 4 + r] = mean;
      srstd[mbase + q * 4 + r] = rsqrtf(var + 1e-6f);
    }
  }
  __syncthreads();

  // ---- GEMM2: Z[16x128] = silu(LN(H)) @ W2^T ; normalize-on-load A' frags ----
  short8 af2[12];
  {
    int e = mbase + col;
    float mean = smean[e], rstd = srstd[e];
    #pragma unroll
    for (int kt = 0; kt < 12; ++kt) {
      int kb = kt * 32 + q * 8;
      short8 h8 = *(const short8*)(sf + e * SFA + kb);
      float4 g0 = *(const float4*)(ig + kb),  g1 = *(const float4*)(ig + kb + 4);
      float4 b0 = *(const float4*)(ibn + kb), b1v = *(const float4*)(ibn + kb + 4);
      float G[8] = {g0.x, g0.y, g0.z, g0.w, g1.x, g1.y, g1.z, g1.w};
      float B[8] = {b0.x, b0.y, b0.z, b0.w, b1v.x, b1v.y, b1v.z, b1v.w};
      short8 pk;
      #pragma unroll
      for (int j = 0; j < 8; ++j) {
        float h = bf2f((unsigned short)h8[j]);
        float hn = (h - mean) * rstd * G[j] + B[j];
        pk[j] = (short)f2bf(silu_f(hn));
      }
      af2[kt] = pk;
    }
  }
  {
    short8 bfA[12], bfB[12];
    #pragma unroll
    for (int kt = 0; kt < 12; ++kt)
      bfA[kt] = *(const short8*)(Bsw2 + (((0 * 12 + kt) * 64 + lane) << 3));
    #pragma unroll 1
    for (int ntp = 0; ntp < 4; ++ntp) {
      const int nt0 = 2 * ntp, nt1 = nt0 + 1;
      const bool pf = (ntp < 3);
      {  // nt0: consume bfA, prefetch nt1 -> bfB
        int n = nt0 * 16 + col;
        float biasv = ib2[n];
        f32x4 acc;
        #pragma unroll
        for (int r = 0; r < 4; ++r) acc[r] = biasv;
        #pragma unroll
        for (int kt = 0; kt < 12; ++kt) {
          bfB[kt] = *(const short8*)(Bsw2 + (((nt1 * 12 + kt) * 64 + lane) << 3));
          acc = __builtin_amdgcn_mfma_f32_16x16x32_bf16(af2[kt], bfA[kt], acc, 0, 0, 0);
        }
        #pragma unroll
        for (int r = 0; r < 4; ++r) {
          int ge = geb + mbase + q * 4 + r;
          if (ge < E) atomicAdd(node_out + (size_t)drow[r] * 128 + n, acc[r]);
        }
      }
      {  // nt1: consume bfB, prefetch nt0+2 -> bfA
        int n = nt1 * 16 + col;
        float biasv = ib2[n];
        f32x4 acc;
        #pragma unroll
        for (int r = 0; r < 4; ++r) acc[r] = biasv;
        #pragma unroll
        for (int kt = 0; kt < 12; ++kt) {
          if (pf)
            bfA[kt] = *(const short8*)(Bsw2 + ((((nt0 + 2) * 12 + kt) * 64 + lane) << 3));
          acc = __builtin_amdgcn_mfma_f32_16x16x32_bf16(af2[kt], bfB[kt], acc, 0, 0, 0);
        }
        #pragma unroll
        for (int r = 0; r < 4; ++r) {
          int ge = geb + mbase + q * 4 + r;
          if (ge < E) atomicAdd(node_out + (size_t)drow[r] * 128 + n, acc[r]);
        }
      }
    }
  }
}

__global__ __launch_bounds__(256, 3)
void k_mrg(const float* __restrict__ node, const float* __restrict__ el,
           const int* __restrict__ src, const int* __restrict__ dst,
           const float* __restrict__ mb1, const float* __restrict__ mg,
           const float* __restrict__ mbn, const float* __restrict__ mb2,
           const unsigned short* __restrict__ Bsw3, const unsigned short* __restrict__ Bsw4,
           float* __restrict__ edge_out, int E) {
  __shared__ __attribute__((aligned(16))) unsigned short sf[64 * SFB];  // 41984 B
  __shared__ float smean[64], srstd[64];
  __shared__ int ssrc[64], sdst[64];

  const int t = threadIdx.x;
  const int lane = t & 63;
  const int q = (lane >> 4) & 3;
  const int col = lane & 15;
  const int mbase = (t >> 6) * 16;
  const int geb = blockIdx.x * 64;

  if (t < 64) {
    int ge = geb + t;
    int ok = ge < E;
    ssrc[t] = ok ? src[ge] : 0;
    sdst[t] = ok ? dst[ge] : 0;
  }
  __syncthreads();

  // stage [64][320]: node[src] | node[dst] | el
  #pragma unroll
  for (int ii = 0; ii < 10; ++ii) {
    int cid = t + 256 * ii;          // 2560 chunks
    int e = cid / 40, c0 = (cid % 40) * 8;
    int ge = geb + e;
    float v[8];
    const float* sp;
    if (c0 < 128)       sp = node + (size_t)ssrc[e] * 128 + c0;
    else if (c0 < 256)  sp = node + (size_t)sdst[e] * 128 + (c0 - 128);
    else                sp = el + (size_t)ge * 64 + (c0 - 256);
    if (ge < E) {
      float4 p0 = *(const float4*)sp;
      float4 p1 = *(const float4*)(sp + 4);
      v[0] = p0.x; v[1] = p0.y; v[2] = p0.z; v[3] = p0.w;
      v[4] = p1.x; v[5] = p1.y; v[6] = p1.z; v[7] = p1.w;
    } else {
      #pragma unroll
      for (int j = 0; j < 8; ++j) v[j] = 0.f;
    }
    short8 pk;
    #pragma unroll
    for (int j = 0; j < 8; ++j) pk[j] = (short)f2bf(v[j]);
    *(short8*)(sf + e * SFB + c0) = pk;
  }
  __syncthreads();

  // GEMM1: K=320 (10 kt), N=128 (8 nt); double-buffered B stream
  short8 af[10];
  #pragma unroll
  for (int kt = 0; kt < 10; ++kt)
    af[kt] = *(const short8*)(sf + (mbase + col) * SFB + kt * 32 + q * 8);

  float sums[4] = {0, 0, 0, 0}, sqs[4] = {0, 0, 0, 0};
  {
    short8 bfA[10], bfB[10];
    #pragma unroll
    for (int kt = 0; kt < 10; ++kt)
      bfA[kt] = *(const short8*)(Bsw3 + (((0 * 10 + kt) * 64 + lane) << 3));
    #pragma unroll 1
    for (int ntp = 0; ntp < 4; ++ntp) {
      const int nt0 = 2 * ntp, nt1 = nt0 + 1;
      const bool pf = (ntp < 3);
      {  // nt0
        int n = nt0 * 16 + col;
        float biasv = mb1[n];
        f32x4 acc;
        #pragma unroll
        for (int r = 0; r < 4; ++r) acc[r] = biasv;
        #pragma unroll
        for (int kt = 0; kt < 10; ++kt) {
          bfB[kt] = *(const short8*)(Bsw3 + (((nt1 * 10 + kt) * 64 + lane) << 3));
          acc = __builtin_amdgcn_mfma_f32_16x16x32_bf16(af[kt], bfA[kt], acc, 0, 0, 0);
        }
        #pragma unroll
        for (int r = 0; r < 4; ++r) {
          float vv = acc[r];
          sums[r] += vv; sqs[r] += vv * vv;
          sf[(mbase + q * 4 + r) * SFB + nt0 * 16 + col] = f2bf(vv);
        }
      }
      {  // nt1
        int n = nt1 * 16 + col;
        float biasv = mb1[n];
        f32x4 acc;
        #pragma unroll
        for (int r = 0; r < 4; ++r) acc[r] = biasv;
        #pragma unroll
        for (int kt = 0; kt < 10; ++kt) {
          if (pf)
            bfA[kt] = *(const short8*)(Bsw3 + ((((nt0 + 2) * 10 + kt) * 64 + lane) << 3));
          acc = __builtin_amdgcn_mfma_f32_16x16x32_bf16(af[kt], bfB[kt], acc, 0, 0, 0);
        }
        #pragma unroll
        for (int r = 0; r < 4; ++r) {
          float vv = acc[r];
          sums[r] += vv; sqs[r] += vv * vv;
          sf[(mbase + q * 4 + r) * SFB + nt1 * 16 + col] = f2bf(vv);
        }
      }
    }
  }

  #pragma unroll
  for (int r = 0; r < 4; ++r) {
    float s = sums[r], ss = sqs[r];
    for (int m = 1; m < 16; m <<= 1) { s += __shfl_xor(s, m, 64); ss += __shfl_xor(ss, m, 64); }
    sums[r] = s; sqs[r] = ss;
  }
  if (col == 0) {
    #pragma unroll
    for (int r = 0; r < 4; ++r) {
      float mean = sums[r] * (1.f / 128.f);
      float var = sqs[r] * (1.f / 128.f) - mean * mean;
      smean[mbase + q * 4 + r] = mean;
      srstd[mbase + q * 4 + r] = rsqrtf(var + 1e-6f);
    }
  }
  __syncthreads();

  // GEMM2: K=128 (4 kt), N=128 (8 nt); double-buffered B stream
  short8 af2[4];
  {
    int e = mbase + col;
    float mean = smean[e], rstd = srstd[e];
    #pragma unroll
    for (int kt = 0; kt < 4; ++kt) {
      int kb = kt * 32 + q * 8;
      short8 h8 = *(const short8*)(sf + e * SFB + kb);
      float4 g0 = *(const float4*)(mg + kb),  g1 = *(const float4*)(mg + kb + 4);
      float4 b0 = *(const float4*)(mbn + kb), b1v = *(const float4*)(mbn + kb + 4);
      float G[8] = {g0.x, g0.y, g0.z, g0.w, g1.x, g1.y, g1.z, g1.w};
      float B[8] = {b0.x, b0.y, b0.z, b0.w, b1v.x, b1v.y, b1v.z, b1v.w};
      short8 pk;
      #pragma unroll
      for (int j = 0; j < 8; ++j) {
        float h = bf2f((unsigned short)h8[j]);
        float hn = (h - mean) * rstd * G[j] + B[j];
        pk[j] = (short)f2bf(silu_f(hn));
      }
      af2[kt] = pk;
    }
  }
  {
    short8 bfA[4], bfB[4];
    #pragma unroll
    for (int kt = 0; kt < 4; ++kt)
      bfA[kt] = *(const short8*)(Bsw4 + (((0 * 4 + kt) * 64 + lane) << 3));
    #pragma unroll 1
    for (int ntp = 0; ntp < 4; ++ntp) {
      const int nt0 = 2 * ntp, nt1 = nt0 + 1;
      const bool pf = (ntp < 3);
      {  // nt0
        int n = nt0 * 16 + col;
        float biasv = mb2[n];
        f32x4 acc;
        #pragma unroll
        for (int r = 0; r < 4; ++r) acc[r] = biasv;
        #pragma unroll
        for (int kt = 0; kt < 4; ++kt) {
          bfB[kt] = *(const short8*)(Bsw4 + (((nt1 * 4 + kt) * 64 + lane) << 3));
          acc = __builtin_amdgcn_mfma_f32_16x16x32_bf16(af2[kt], bfA[kt], acc, 0, 0, 0);
        }
        #pragma unroll
        for (int r = 0; r < 4; ++r) {
          int ge = geb + mbase + q * 4 + r;
          if (ge < E) edge_out[(size_t)ge * 128 + n] = acc[r];
        }
      }
      {  // nt1
        int n = nt1 * 16 + col;
        float biasv = mb2[n];
        f32x4 acc;
        #pragma unroll
        for (int r = 0; r < 4; ++r) acc[r] = biasv;
        #pragma unroll
        for (int kt = 0; kt < 4; ++kt) {
          if (pf)
            bfA[kt] = *(const short8*)(Bsw4 + ((((nt0 + 2) * 4 + kt) * 64 + lane) << 3));
          acc = __builtin_amdgcn_mfma_f32_16x16x32_bf16(af2[kt], bfB[kt], acc, 0, 0, 0);
        }
        #pragma unroll
        for (int r = 0; r < 4; ++r) {
          int ge = geb + mbase + q * 4 + r;
          if (ge < E) edge_out[(size_t)ge * 128 + n] = acc[r];
        }
      }
    }
  }
}

extern "C" void kernel_launch(void* const* d_in, const int* in_sizes, int n_in,
                              void* d_out, int out_size, void* d_ws, size_t ws_size,
                              hipStream_t stream) {
  const float* atom = (const float*)d_in[0];
  const float* el   = (const float*)d_in[1];
  const float* ev   = (const float*)d_in[2];
  const int*   eidx = (const int*)d_in[3];
  const float* aw1  = (const float*)d_in[4];
  const float* ab1  = (const float*)d_in[5];
  const float* ag   = (const float*)d_in[6];
  const float* abn  = (const float*)d_in[7];
  const float* aw2  = (const float*)d_in[8];
  const float* ab2  = (const float*)d_in[9];
  const float* iw1  = (const float*)d_in[10];
  const float* ib1  = (const float*)d_in[11];
  const float* ig   = (const float*)d_in[12];
  const float* ibn  = (const float*)d_in[13];
  const float* iw2  = (const float*)d_in[14];
  const float* ib2  = (const float*)d_in[15];
  const float* mw1  = (const float*)d_in[16];
  const float* mb1  = (const float*)d_in[17];
  const float* mg   = (const float*)d_in[18];
  const float* mbn  = (const float*)d_in[19];
  const float* mw2  = (const float*)d_in[20];
  const float* mb2  = (const float*)d_in[21];

  const int N = in_sizes[0] / 64;
  const int E = in_sizes[1] / 64;
  const int* src = eidx;
  const int* dst = eidx + E;

  char* ws = (char*)d_ws;
  size_t off = 0;
  int* last_idx = (int*)(ws + off);          off += 256;
  unsigned char* rawmask = (unsigned char*)(ws + off); off += ((size_t)E + 255) & ~(size_t)255;
  float* Wfa  = (float*)(ws + off);          off += (size_t)384 * 64 * 4;
  float* cfa  = (float*)(ws + off);          off += 384 * 4;
  float* wg   = (float*)(ws + off);          off += 256;
  float* bg   = (float*)(ws + off);          off += 256;
  float* angp = (float*)(ws + off);          off += 256;
  unsigned short* B1 = (unsigned short*)(ws + off); off += (size_t)24 * 12 * 64 * 8 * 2;
  unsigned short* B2 = (unsigned short*)(ws + off); off += (size_t)8 * 12 * 64 * 8 * 2;
  unsigned short* B3 = (unsigned short*)(ws + off); off += (size_t)8 * 10 * 64 * 8 * 2;
  unsigned short* B4 = (unsigned short*)(ws + off); off += (size_t)8 * 4 * 64 * 8 * 2;

  float* node_out = (float*)d_out;
  float* edge_out = node_out + (size_t)N * 128;

  const int eb = (E + 255) / 256;
  const int tb = (E + 63) / 64;
  const int swz_n = 24 * 12 * 64 + 8 * 12 * 64 + 8 * 10 * 64 + 8 * 4 * 64;

  k_init<<<2048, 256, 0, stream>>>(node_out, N * 128, last_idx);
  k_mask<<<eb, 256, 0, stream>>>(src, dst, E, rawmask, last_idx);
  k_setup<<<(384 * 64 + 384 + 64 + 255) / 256, 256, 0, stream>>>(
      iw1, aw2, ab2, aw1, ab1, ag, Wfa, cfa, wg, bg, angp);
  k_swz<<<(swz_n + 255) / 256, 256, 0, stream>>>(iw1, iw2, mw1, mw2, Wfa, B1, B2, B3, B4);
  k_inv<<<tb, 256, 0, stream>>>(atom, el, ev, src, dst, rawmask, last_idx,
                                ib1, ig, ibn, ib2, cfa, wg, bg, abn, angp,
                                B1, B2, node_out, E);
  k_mrg<<<tb, 256, 0, stream>>>(node_out, el, src, dst,
                                mb1, mg, mbn, mb2, B3, B4, edge_out, E);
}

// Round 6
// 1170.827 us; speedup vs baseline: 2.4947x; 1.0048x over previous
//
#include <hip/hip_runtime.h>
#include <math.h>

// Round 7: isolate R6's correctness failure (absmax 17 vs 0.425).
// Suspect: v_cvt_pk_bf16_f32 inline-asm operand order (S0/S1 -> lo/hi) —
// a pairwise swap of staged feat values vs unswapped weights explains the
// garbage-magnitude error. Revert ALL hot conversions to the proven software
// f2bf (RTNE, R3 passed with absmax 0.125); KEEP the 4-thread/edge
// division-free staging and k_inv __launch_bounds__(256,3).

typedef short short8 __attribute__((ext_vector_type(8)));
typedef float f32x4 __attribute__((ext_vector_type(4)));

#define SFA 392   // k_inv feat row stride (ushorts); 784B -> 196 dwords, 196%32=4 -> 2-way
#define SFB 328   // k_mrg feat row stride (ushorts); 656B -> 164 dwords, 164%32=4 -> 2-way

__device__ __forceinline__ unsigned short f2bf(float x) {
  union { float f; unsigned u; } v; v.f = x;
  unsigned r = (v.u + 0x7FFFu + ((v.u >> 16) & 1u)) >> 16;
  return (unsigned short)r;
}
__device__ __forceinline__ float bf2f(unsigned short h) {
  union { unsigned u; float f; } v; v.u = ((unsigned)h) << 16;
  return v.f;
}
__device__ __forceinline__ float silu_f(float x) { return x / (1.0f + __expf(-x)); }

__global__ void k_init(float* __restrict__ node_out, int n, int* __restrict__ last_idx) {
  int i = blockIdx.x * blockDim.x + threadIdx.x;
  if (i == 0) *last_idx = -1;
  for (; i < n; i += gridDim.x * blockDim.x) node_out[i] = 0.0f;
}

__global__ void k_mask(const int* __restrict__ src, const int* __restrict__ dst,
                       int E, unsigned char* __restrict__ rawmask, int* __restrict__ last_idx) {
  int i = blockIdx.x * blockDim.x + threadIdx.x;
  if (i >= E) return;
  int s0 = src[i], d0 = dst[i];
  int s1 = (i + 1 < E) ? src[i + 1] : 0;   // _shift pads 0
  int d1 = (i + 1 < E) ? dst[i + 1] : 0;
  int m = (s0 == s1) && (s0 != d0) && (s1 != d1);
  rawmask[i] = (unsigned char)m;
  if (m) atomicMax(last_idx, i);
}

// Wfa = iw1[:,320:]@aw2 ; cfa = iw1[:,320:]@ab2 ; angle closed-form LN folds.
__global__ void k_setup(const float* __restrict__ iw1, const float* __restrict__ aw2,
                        const float* __restrict__ ab2,
                        const float* __restrict__ aw1, const float* __restrict__ ab1,
                        const float* __restrict__ ag,
                        float* __restrict__ Wfa, float* __restrict__ cfa,
                        float* __restrict__ wg, float* __restrict__ bg,
                        float* __restrict__ angp) {
  int n = blockIdx.x * blockDim.x + threadIdx.x;
  if (n < 384 * 64) {
    int r = n >> 6, j = n & 63;
    float acc = 0.0f;
    for (int k = 0; k < 64; ++k) acc += iw1[r * 384 + 320 + k] * aw2[k * 64 + j];
    Wfa[n] = acc;
  } else if (n < 384 * 64 + 384) {
    int r = n - 384 * 64;
    float acc = 0.0f;
    for (int k = 0; k < 64; ++k) acc += iw1[r * 384 + 320 + k] * ab2[k];
    cfa[r] = acc;
  } else if (n < 384 * 64 + 384 + 64) {
    int j = n - (384 * 64 + 384);
    float wm = 0.f, bm = 0.f;
    for (int k = 0; k < 64; ++k) { wm += aw1[k]; bm += ab1[k]; }
    wm *= (1.f / 64.f); bm *= (1.f / 64.f);
    wg[j] = (aw1[j] - wm) * ag[j];
    bg[j] = (ab1[j] - bm) * ag[j];
    if (j == 0) {
      float vw = 0.f, cwb = 0.f, vb = 0.f;
      for (int k = 0; k < 64; ++k) {
        float dw = aw1[k] - wm, db = ab1[k] - bm;
        vw += dw * dw; cwb += dw * db; vb += db * db;
      }
      angp[0] = vw * (1.f / 64.f);
      angp[1] = cwb * (1.f / 64.f);
      angp[2] = vb * (1.f / 64.f);
    }
  }
}

// Swizzle weights into B-fragment order: B[(nt*KT+kt)*64 + lane][8] with
// value = W[n = nt*16 + (lane&15)][k = kt*32 + ((lane>>4)&3)*8 + j]  (bf16).
__global__ void k_swz(const float* __restrict__ iw1, const float* __restrict__ iw2,
                      const float* __restrict__ mw1, const float* __restrict__ mw2,
                      const float* __restrict__ Wfa,
                      unsigned short* __restrict__ B1, unsigned short* __restrict__ B2,
                      unsigned short* __restrict__ B3, unsigned short* __restrict__ B4) {
  const int NC1 = 24 * 12 * 64, NC2 = 8 * 12 * 64, NC3 = 8 * 10 * 64, NC4 = 8 * 4 * 64;
  int cid = blockIdx.x * blockDim.x + threadIdx.x;
  int region, rel, KT;
  unsigned short* out;
  if (cid < NC1)                    { region = 1; rel = cid;                KT = 12; out = B1; }
  else if (cid < NC1 + NC2)         { region = 2; rel = cid - NC1;          KT = 12; out = B2; }
  else if (cid < NC1 + NC2 + NC3)   { region = 3; rel = cid - NC1 - NC2;    KT = 10; out = B3; }
  else if (cid < NC1 + NC2 + NC3 + NC4) { region = 4; rel = cid - NC1 - NC2 - NC3; KT = 4; out = B4; }
  else return;
  int l = rel & 63;
  int ktn = rel >> 6;
  int kt = ktn % KT, nt = ktn / KT;
  int n = nt * 16 + (l & 15);
  int k0 = kt * 32 + ((l >> 4) & 3) * 8;
  short8 pk;
  #pragma unroll
  for (int j = 0; j < 8; ++j) {
    int k = k0 + j;
    float v;
    if (region == 1)      v = (k < 320) ? iw1[n * 384 + k] : Wfa[n * 64 + (k - 320)];
    else if (region == 2) v = iw2[n * 384 + k];
    else if (region == 3) v = mw1[n * 320 + k];
    else                  v = mw2[n * 128 + k];
    pk[j] = (short)f2bf(v);
  }
  *(short8*)(out + ((size_t)rel << 3)) = pk;
}

__global__ __launch_bounds__(256, 3)
void k_inv(const float* __restrict__ atom, const float* __restrict__ el,
           const float* __restrict__ ev,
           const int* __restrict__ src, const int* __restrict__ dst,
           const unsigned char* __restrict__ rawmask, const int* __restrict__ last_idx,
           const float* __restrict__ ib1, const float* __restrict__ ig,
           const float* __restrict__ ibn, const float* __restrict__ ib2,
           const float* __restrict__ cfa, const float* __restrict__ wg,
           const float* __restrict__ bg, const float* __restrict__ abn,
           const float* __restrict__ angp,
           const unsigned short* __restrict__ Bsw1, const unsigned short* __restrict__ Bsw2,
           float* __restrict__ node_out, int E) {
  __shared__ __attribute__((aligned(16))) unsigned short sf[64 * SFA];  // 50176 B
  __shared__ float scos[64], srr[64], smaskf[64], smean[64], srstd[64];
  __shared__ int ssrc[64], sdst[64], sdsts[64];

  const int t = threadIdx.x;
  const int lane = t & 63;
  const int q = (lane >> 4) & 3;
  const int col = lane & 15;
  const int mbase = (t >> 6) * 16;
  const int geb = blockIdx.x * 64;

  // ---- pre-pass: per-edge mask, indices, cos, closed-form LN rstd ----
  if (t < 64) {
    int e = t, ge = geb + e;
    int last = *last_idx;
    int ok = ge < E;
    int m0 = 0, m1 = 0, s0 = 0, d0 = 0, d1 = 0;
    if (ok) { s0 = src[ge]; d0 = dst[ge]; m0 = rawmask[ge] && (ge != last); }
    if (ge + 1 < E) { d1 = dst[ge + 1]; m1 = rawmask[ge + 1] && (ge + 1 != last); }
    ssrc[e] = s0; sdst[e] = d0; sdsts[e] = d1;
    smaskf[e] = m0 ? 1.0f : 0.0f;
    float cosv = 0.f;
    if (m0 && m1) {
      float ax = ev[3 * ge], ay = ev[3 * ge + 1], az = ev[3 * ge + 2];
      float bx = ev[3 * ge + 3], by = ev[3 * ge + 4], bz = ev[3 * ge + 5];
      cosv = (ax * bx + ay * by + az * bz) *
             rsqrtf((ax * ax + ay * ay + az * az) * (bx * bx + by * by + bz * bz));
    }
    scos[e] = cosv;
    srr[e] = rsqrtf(cosv * cosv * angp[0] + 2.f * cosv * angp[1] + angp[2] + 1e-6f);
  }
  __syncthreads();

  // ---- stage feat [64][384] bf16 into LDS: 4 threads/edge, division-free ----
  // mk>0 implies ge < E and ge+1 < E (rawmask[E-1]=0 by _shift pad, ge!=last),
  // so no per-chunk bounds checks are needed on the loaded path.
  {
    const int es = t >> 2, sub = t & 3;
    const int ge = geb + es;
    const float mk = smaskf[es];
    unsigned short* drw = sf + es * SFA;
    if (mk > 0.f) {
      const float* p0 = atom + (size_t)ssrc[es] * 64 + sub * 8;
      const float* p1 = atom + (size_t)sdst[es] * 64 + sub * 8;
      const float* p2 = el + (size_t)ge * 64 + sub * 8;
      const float* p3 = atom + (size_t)sdsts[es] * 64 + sub * 8;
      const float* p4 = el + (size_t)(ge + 1) * 64 + sub * 8;
      auto stage8 = [&](int colb, const float* sp) {
        float4 a = *(const float4*)sp;
        float4 b = *(const float4*)(sp + 4);
        short8 pk;
        pk[0] = (short)f2bf(a.x); pk[1] = (short)f2bf(a.y);
        pk[2] = (short)f2bf(a.z); pk[3] = (short)f2bf(a.w);
        pk[4] = (short)f2bf(b.x); pk[5] = (short)f2bf(b.y);
        pk[6] = (short)f2bf(b.z); pk[7] = (short)f2bf(b.w);
        *(short8*)(drw + colb) = pk;
      };
      stage8(sub * 8,        p0);  stage8(32 + sub * 8,  p0 + 32);
      stage8(64 + sub * 8,   p1);  stage8(96 + sub * 8,  p1 + 32);
      stage8(128 + sub * 8,  p2);  stage8(160 + sub * 8, p2 + 32);
      stage8(192 + sub * 8,  p3);  stage8(224 + sub * 8, p3 + 32);
      stage8(256 + sub * 8,  p4);  stage8(288 + sub * 8, p4 + 32);
      // angle cols 320..383, closed-form (mk == 1 here)
      const float cosv = scos[es], rr = srr[es];
      #pragma unroll
      for (int ii = 0; ii < 2; ++ii) {
        const int j0 = sub * 8 + ii * 32;
        float4 w0 = *(const float4*)(wg + j0),  w1 = *(const float4*)(wg + j0 + 4);
        float4 g0 = *(const float4*)(bg + j0),  g1 = *(const float4*)(bg + j0 + 4);
        float4 n0 = *(const float4*)(abn + j0), n1 = *(const float4*)(abn + j0 + 4);
        short8 pk;
        pk[0] = (short)f2bf(silu_f((cosv * w0.x + g0.x) * rr + n0.x));
        pk[1] = (short)f2bf(silu_f((cosv * w0.y + g0.y) * rr + n0.y));
        pk[2] = (short)f2bf(silu_f((cosv * w0.z + g0.z) * rr + n0.z));
        pk[3] = (short)f2bf(silu_f((cosv * w0.w + g0.w) * rr + n0.w));
        pk[4] = (short)f2bf(silu_f((cosv * w1.x + g1.x) * rr + n1.x));
        pk[5] = (short)f2bf(silu_f((cosv * w1.y + g1.y) * rr + n1.y));
        pk[6] = (short)f2bf(silu_f((cosv * w1.z + g1.z) * rr + n1.z));
        pk[7] = (short)f2bf(silu_f((cosv * w1.w + g1.w) * rr + n1.w));
        *(short8*)(drw + 320 + j0) = pk;
      }
    } else {
      short8 z = {0, 0, 0, 0, 0, 0, 0, 0};
      #pragma unroll
      for (int ii = 0; ii < 12; ++ii)
        *(short8*)(drw + sub * 8 + ii * 32) = z;
    }
  }
  __syncthreads();

  // ---- GEMM1: H[16x384] = feat @ W1eff^T, per wave; double-buffered B stream ----
  short8 af[12];
  #pragma unroll
  for (int kt = 0; kt < 12; ++kt)
    af[kt] = *(const short8*)(sf + (mbase + col) * SFA + kt * 32 + q * 8);

  float mrow[4]; int drow[4];
  #pragma unroll
  for (int r = 0; r < 4; ++r) {
    int e = mbase + q * 4 + r;
    mrow[r] = smaskf[e];
    drow[r] = sdst[e];
  }

  float sums[4] = {0, 0, 0, 0}, sqs[4] = {0, 0, 0, 0};
  {
    short8 bfA[12], bfB[12];
    #pragma unroll
    for (int kt = 0; kt < 12; ++kt)
      bfA[kt] = *(const short8*)(Bsw1 + (((0 * 12 + kt) * 64 + lane) << 3));
    #pragma unroll 1
    for (int ntp = 0; ntp < 12; ++ntp) {
      const int nt0 = 2 * ntp, nt1 = nt0 + 1;
      const bool pf = (ntp < 11);
      {  // nt0: consume bfA, prefetch nt1 -> bfB
        int n = nt0 * 16 + col;
        float biasv = ib1[n], cfav = cfa[n];
        f32x4 acc;
        #pragma unroll
        for (int r = 0; r < 4; ++r) acc[r] = biasv + mrow[r] * cfav;
        #pragma unroll
        for (int kt = 0; kt < 12; ++kt) {
          bfB[kt] = *(const short8*)(Bsw1 + (((nt1 * 12 + kt) * 64 + lane) << 3));
          acc = __builtin_amdgcn_mfma_f32_16x16x32_bf16(af[kt], bfA[kt], acc, 0, 0, 0);
        }
        #pragma unroll
        for (int r = 0; r < 4; ++r) {
          float vv = acc[r];
          sums[r] += vv; sqs[r] += vv * vv;
          sf[(mbase + q * 4 + r) * SFA + nt0 * 16 + col] = f2bf(vv);
        }
      }
      {  // nt1: consume bfB, prefetch nt0+2 -> bfA
        int n = nt1 * 16 + col;
        float biasv = ib1[n], cfav = cfa[n];
        f32x4 acc;
        #pragma unroll
        for (int r = 0; r < 4; ++r) acc[r] = biasv + mrow[r] * cfav;
        #pragma unroll
        for (int kt = 0; kt < 12; ++kt) {
          if (pf)
            bfA[kt] = *(const short8*)(Bsw1 + ((((nt0 + 2) * 12 + kt) * 64 + lane) << 3));
          acc = __builtin_amdgcn_mfma_f32_16x16x32_bf16(af[kt], bfB[kt], acc, 0, 0, 0);
        }
        #pragma unroll
        for (int r = 0; r < 4; ++r) {
          float vv = acc[r];
          sums[r] += vv; sqs[r] += vv * vv;
          sf[(mbase + q * 4 + r) * SFA + nt1 * 16 + col] = f2bf(vv);
        }
      }
    }
  }

  // intra-quad (16-lane) reduction for per-edge LN stats
  #pragma unroll
  for (int r = 0; r < 4; ++r) {
    float s = sums[r], ss = sqs[r];
    for (int m = 1; m < 16; m <<= 1) { s += __shfl_xor(s, m, 64); ss += __shfl_xor(ss, m, 64); }
    sums[r] = s; sqs[r] = ss;
  }
  if (col == 0) {
    #pragma unroll
    for (int r = 0; r < 4; ++r) {
      float mean = sums[r] * (1.f / 384.f);
      float var = sqs[r] * (1.f / 384.f) - mean * mean;
      smean[mbase + q * 4 + r] = mean;
      srstd[mbase + q * 4 + r] = rsqrtf(var + 1e-6f);
    }
  }
  __syncthreads();

  // ---- GEMM2: Z[16x128] = silu(LN(H)) @ W2^T ; normalize-on-load A' frags ----
  short8 af2[12];
  {
    int e = mbase + col;
    float mean = smean[e], rstd = srstd[e];
    #pragma unroll
    for (int kt = 0; kt < 12; ++kt) {
      int kb = kt * 32 + q * 8;
      short8 h8 = *(const short8*)(sf + e * SFA + kb);
      float4 g0 = *(const float4*)(ig + kb),  g1 = *(const float4*)(ig + kb + 4);
      float4 b0 = *(const float4*)(ibn + kb), b1v = *(const float4*)(ibn + kb + 4);
      float G[8] = {g0.x, g0.y, g0.z, g0.w, g1.x, g1.y, g1.z, g1.w};
      float B[8] = {b0.x, b0.y, b0.z, b0.w, b1v.x, b1v.y, b1v.z, b1v.w};
      short8 pk;
      #pragma unroll
      for (int j = 0; j < 8; ++j) {
        float h = bf2f((unsigned short)h8[j]);
        float hn = (h - mean) * rstd * G[j] + B[j];
        pk[j] = (short)f2bf(silu_f(hn));
      }
      af2[kt] = pk;
    }
  }
  {
    short8 bfA[12], bfB[12];
    #pragma unroll
    for (int kt = 0; kt < 12; ++kt)
      bfA[kt] = *(const short8*)(Bsw2 + (((0 * 12 + kt) * 64 + lane) << 3));
    #pragma unroll 1
    for (int ntp = 0; ntp < 4; ++ntp) {
      const int nt0 = 2 * ntp, nt1 = nt0 + 1;
      const bool pf = (ntp < 3);
      {  // nt0: consume bfA, prefetch nt1 -> bfB
        int n = nt0 * 16 + col;
        float biasv = ib2[n];
        f32x4 acc;
        #pragma unroll
        for (int r = 0; r < 4; ++r) acc[r] = biasv;
        #pragma unroll
        for (int kt = 0; kt < 12; ++kt) {
          bfB[kt] = *(const short8*)(Bsw2 + (((nt1 * 12 + kt) * 64 + lane) << 3));
          acc = __builtin_amdgcn_mfma_f32_16x16x32_bf16(af2[kt], bfA[kt], acc, 0, 0, 0);
        }
        #pragma unroll
        for (int r = 0; r < 4; ++r) {
          int ge = geb + mbase + q * 4 + r;
          if (ge < E) atomicAdd(node_out + (size_t)drow[r] * 128 + n, acc[r]);
        }
      }
      {  // nt1: consume bfB, prefetch nt0+2 -> bfA
        int n = nt1 * 16 + col;
        float biasv = ib2[n];
        f32x4 acc;
        #pragma unroll
        for (int r = 0; r < 4; ++r) acc[r] = biasv;
        #pragma unroll
        for (int kt = 0; kt < 12; ++kt) {
          if (pf)
            bfA[kt] = *(const short8*)(Bsw2 + ((((nt0 + 2) * 12 + kt) * 64 + lane) << 3));
          acc = __builtin_amdgcn_mfma_f32_16x16x32_bf16(af2[kt], bfB[kt], acc, 0, 0, 0);
        }
        #pragma unroll
        for (int r = 0; r < 4; ++r) {
          int ge = geb + mbase + q * 4 + r;
          if (ge < E) atomicAdd(node_out + (size_t)drow[r] * 128 + n, acc[r]);
        }
      }
    }
  }
}

__global__ __launch_bounds__(256, 3)
void k_mrg(const float* __restrict__ node, const float* __restrict__ el,
           const int* __restrict__ src, const int* __restrict__ dst,
           const float* __restrict__ mb1, const float* __restrict__ mg,
           const float* __restrict__ mbn, const float* __restrict__ mb2,
           const unsigned short* __restrict__ Bsw3, const unsigned short* __restrict__ Bsw4,
           float* __restrict__ edge_out, int E) {
  __shared__ __attribute__((aligned(16))) unsigned short sf[64 * SFB];  // 41984 B
  __shared__ float smean[64], srstd[64];
  __shared__ int ssrc[64], sdst[64];

  const int t = threadIdx.x;
  const int lane = t & 63;
  const int q = (lane >> 4) & 3;
  const int col = lane & 15;
  const int mbase = (t >> 6) * 16;
  const int geb = blockIdx.x * 64;

  if (t < 64) {
    int ge = geb + t;
    int ok = ge < E;
    ssrc[t] = ok ? src[ge] : 0;
    sdst[t] = ok ? dst[ge] : 0;
  }
  __syncthreads();

  // ---- stage [64][320]: node[src] | node[dst] | el ; 4 threads/edge ----
  {
    const int es = t >> 2, sub = t & 3;
    const int ge = geb + es;
    unsigned short* drw = sf + es * SFB;
    if (ge < E) {
      const float* p0 = node + (size_t)ssrc[es] * 128 + sub * 8;
      const float* p1 = node + (size_t)sdst[es] * 128 + sub * 8;
      const float* p2 = el + (size_t)ge * 64 + sub * 8;
      auto stage8 = [&](int colb, const float* sp) {
        float4 a = *(const float4*)sp;
        float4 b = *(const float4*)(sp + 4);
        short8 pk;
        pk[0] = (short)f2bf(a.x); pk[1] = (short)f2bf(a.y);
        pk[2] = (short)f2bf(a.z); pk[3] = (short)f2bf(a.w);
        pk[4] = (short)f2bf(b.x); pk[5] = (short)f2bf(b.y);
        pk[6] = (short)f2bf(b.z); pk[7] = (short)f2bf(b.w);
        *(short8*)(drw + colb) = pk;
      };
      stage8(sub * 8,        p0);       stage8(32 + sub * 8,  p0 + 32);
      stage8(64 + sub * 8,   p0 + 64);  stage8(96 + sub * 8,  p0 + 96);
      stage8(128 + sub * 8,  p1);       stage8(160 + sub * 8, p1 + 32);
      stage8(192 + sub * 8,  p1 + 64);  stage8(224 + sub * 8, p1 + 96);
      stage8(256 + sub * 8,  p2);       stage8(288 + sub * 8, p2 + 32);
    } else {
      short8 z = {0, 0, 0, 0, 0, 0, 0, 0};
      #pragma unroll
      for (int ii = 0; ii < 10; ++ii)
        *(short8*)(drw + sub * 8 + ii * 32) = z;
    }
  }
  __syncthreads();

  // GEMM1: K=320 (10 kt), N=128 (8 nt); double-buffered B stream
  short8 af[10];
  #pragma unroll
  for (int kt = 0; kt < 10; ++kt)
    af[kt] = *(const short8*)(sf + (mbase + col) * SFB + kt * 32 + q * 8);

  float sums[4] = {0, 0, 0, 0}, sqs[4] = {0, 0, 0, 0};
  {
    short8 bfA[10], bfB[10];
    #pragma unroll
    for (int kt = 0; kt < 10; ++kt)
      bfA[kt] = *(const short8*)(Bsw3 + (((0 * 10 + kt) * 64 + lane) << 3));
    #pragma unroll 1
    for (int ntp = 0; ntp < 4; ++ntp) {
      const int nt0 = 2 * ntp, nt1 = nt0 + 1;
      const bool pf = (ntp < 3);
      {  // nt0
        int n = nt0 * 16 + col;
        float biasv = mb1[n];
        f32x4 acc;
        #pragma unroll
        for (int r = 0; r < 4; ++r) acc[r] = biasv;
        #pragma unroll
        for (int kt = 0; kt < 10; ++kt) {
          bfB[kt] = *(const short8*)(Bsw3 + (((nt1 * 10 + kt) * 64 + lane) << 3));
          acc = __builtin_amdgcn_mfma_f32_16x16x32_bf16(af[kt], bfA[kt], acc, 0, 0, 0);
        }
        #pragma unroll
        for (int r = 0; r < 4; ++r) {
          float vv = acc[r];
          sums[r] += vv; sqs[r] += vv * vv;
          sf[(mbase + q * 4 + r) * SFB + nt0 * 16 + col] = f2bf(vv);
        }
      }
      {  // nt1
        int n = nt1 * 16 + col;
        float biasv = mb1[n];
        f32x4 acc;
        #pragma unroll
        for (int r = 0; r < 4; ++r) acc[r] = biasv;
        #pragma unroll
        for (int kt = 0; kt < 10; ++kt) {
          if (pf)
            bfA[kt] = *(const short8*)(Bsw3 + ((((nt0 + 2) * 10 + kt) * 64 + lane) << 3));
          acc = __builtin_amdgcn_mfma_f32_16x16x32_bf16(af[kt], bfB[kt], acc, 0, 0, 0);
        }
        #pragma unroll
        for (int r = 0; r < 4; ++r) {
          float vv = acc[r];
          sums[r] += vv; sqs[r] += vv * vv;
          sf[(mbase + q * 4 + r) * SFB + nt1 * 16 + col] = f2bf(vv);
        }
      }
    }
  }

  #pragma unroll
  for (int r = 0; r < 4; ++r) {
    float s = sums[r], ss = sqs[r];
    for (int m = 1; m < 16; m <<= 1) { s += __shfl_xor(s, m, 64); ss += __shfl_xor(ss, m, 64); }
    sums[r] = s; sqs[r] = ss;
  }
  if (col == 0) {
    #pragma unroll
    for (int r = 0; r < 4; ++r) {
      float mean = sums[r] * (1.f / 128.f);
      float var = sqs[r] * (1.f / 128.f) - mean * mean;
      smean[mbase + q * 4 + r] = mean;
      srstd[mbase + q * 4 + r] = rsqrtf(var + 1e-6f);
    }
  }
  __syncthreads();

  // GEMM2: K=128 (4 kt), N=128 (8 nt); double-buffered B stream
  short8 af2[4];
  {
    int e = mbase + col;
    float mean = smean[e], rstd = srstd[e];
    #pragma unroll
    for (int kt = 0; kt < 4; ++kt) {
      int kb = kt * 32 + q * 8;
      short8 h8 = *(const short8*)(sf + e * SFB + kb);
      float4 g0 = *(const float4*)(mg + kb),  g1 = *(const float4*)(mg + kb + 4);
      float4 b0 = *(const float4*)(mbn + kb), b1v = *(const float4*)(mbn + kb + 4);
      float G[8] = {g0.x, g0.y, g0.z, g0.w, g1.x, g1.y, g1.z, g1.w};
      float B[8] = {b0.x, b0.y, b0.z, b0.w, b1v.x, b1v.y, b1v.z, b1v.w};
      short8 pk;
      #pragma unroll
      for (int j = 0; j < 8; ++j) {
        float h = bf2f((unsigned short)h8[j]);
        float hn = (h - mean) * rstd * G[j] + B[j];
        pk[j] = (short)f2bf(silu_f(hn));
      }
      af2[kt] = pk;
    }
  }
  {
    short8 bfA[4], bfB[4];
    #pragma unroll
    for (int kt = 0; kt < 4; ++kt)
      bfA[kt] = *(const short8*)(Bsw4 + (((0 * 4 + kt) * 64 + lane) << 3));
    #pragma unroll 1
    for (int ntp = 0; ntp < 4; ++ntp) {
      const int nt0 = 2 * ntp, nt1 = nt0 + 1;
      const bool pf = (ntp < 3);
      {  // nt0
        int n = nt0 * 16 + col;
        float biasv = mb2[n];
        f32x4 acc;
        #pragma unroll
        for (int r = 0; r < 4; ++r) acc[r] = biasv;
        #pragma unroll
        for (int kt = 0; kt < 4; ++kt) {
          bfB[kt] = *(const short8*)(Bsw4 + (((nt1 * 4 + kt) * 64 + lane) << 3));
          acc = __builtin_amdgcn_mfma_f32_16x16x32_bf16(af2[kt], bfA[kt], acc, 0, 0, 0);
        }
        #pragma unroll
        for (int r = 0; r < 4; ++r) {
          int ge = geb + mbase + q * 4 + r;
          if (ge < E) edge_out[(size_t)ge * 128 + n] = acc[r];
        }
      }
      {  // nt1
        int n = nt1 * 16 + col;
        float biasv = mb2[n];
        f32x4 acc;
        #pragma unroll
        for (int r = 0; r < 4; ++r) acc[r] = biasv;
        #pragma unroll
        for (int kt = 0; kt < 4; ++kt) {
          if (pf)
            bfA[kt] = *(const short8*)(Bsw4 + ((((nt0 + 2) * 4 + kt) * 64 + lane) << 3));
          acc = __builtin_amdgcn_mfma_f32_16x16x32_bf16(af2[kt], bfB[kt], acc, 0, 0, 0);
        }
        #pragma unroll
        for (int r = 0; r < 4; ++r) {
          int ge = geb + mbase + q * 4 + r;
          if (ge < E) edge_out[(size_t)ge * 128 + n] = acc[r];
        }
      }
    }
  }
}

extern "C" void kernel_launch(void* const* d_in, const int* in_sizes, int n_in,
                              void* d_out, int out_size, void* d_ws, size_t ws_size,
                              hipStream_t stream) {
  const float* atom = (const float*)d_in[0];
  const float* el   = (const float*)d_in[1];
  const float* ev   = (const float*)d_in[2];
  const int*   eidx = (const int*)d_in[3];
  const float* aw1  = (const float*)d_in[4];
  const float* ab1  = (const float*)d_in[5];
  const float* ag   = (const float*)d_in[6];
  const float* abn  = (const float*)d_in[7];
  const float* aw2  = (const float*)d_in[8];
  const float* ab2  = (const float*)d_in[9];
  const float* iw1  = (const float*)d_in[10];
  const float* ib1  = (const float*)d_in[11];
  const float* ig   = (const float*)d_in[12];
  const float* ibn  = (const float*)d_in[13];
  const float* iw2  = (const float*)d_in[14];
  const float* ib2  = (const float*)d_in[15];
  const float* mw1  = (const float*)d_in[16];
  const float* mb1  = (const float*)d_in[17];
  const float* mg   = (const float*)d_in[18];
  const float* mbn  = (const float*)d_in[19];
  const float* mw2  = (const float*)d_in[20];
  const float* mb2  = (const float*)d_in[21];

  const int N = in_sizes[0] / 64;
  const int E = in_sizes[1] / 64;
  const int* src = eidx;
  const int* dst = eidx + E;

  char* ws = (char*)d_ws;
  size_t off = 0;
  int* last_idx = (int*)(ws + off);          off += 256;
  unsigned char* rawmask = (unsigned char*)(ws + off); off += ((size_t)E + 255) & ~(size_t)255;
  float* Wfa  = (float*)(ws + off);          off += (size_t)384 * 64 * 4;
  float* cfa  = (float*)(ws + off);          off += 384 * 4;
  float* wg   = (float*)(ws + off);          off += 256;
  float* bg   = (float*)(ws + off);          off += 256;
  float* angp = (float*)(ws + off);          off += 256;
  unsigned short* B1 = (unsigned short*)(ws + off); off += (size_t)24 * 12 * 64 * 8 * 2;
  unsigned short* B2 = (unsigned short*)(ws + off); off += (size_t)8 * 12 * 64 * 8 * 2;
  unsigned short* B3 = (unsigned short*)(ws + off); off += (size_t)8 * 10 * 64 * 8 * 2;
  unsigned short* B4 = (unsigned short*)(ws + off); off += (size_t)8 * 4 * 64 * 8 * 2;

  float* node_out = (float*)d_out;
  float* edge_out = node_out + (size_t)N * 128;

  const int eb = (E + 255) / 256;
  const int tb = (E + 63) / 64;
  const int swz_n = 24 * 12 * 64 + 8 * 12 * 64 + 8 * 10 * 64 + 8 * 4 * 64;

  k_init<<<2048, 256, 0, stream>>>(node_out, N * 128, last_idx);
  k_mask<<<eb, 256, 0, stream>>>(src, dst, E, rawmask, last_idx);
  k_setup<<<(384 * 64 + 384 + 64 + 255) / 256, 256, 0, stream>>>(
      iw1, aw2, ab2, aw1, ab1, ag, Wfa, cfa, wg, bg, angp);
  k_swz<<<(swz_n + 255) / 256, 256, 0, stream>>>(iw1, iw2, mw1, mw2, Wfa, B1, B2, B3, B4);
  k_inv<<<tb, 256, 0, stream>>>(atom, el, ev, src, dst, rawmask, last_idx,
                                ib1, ig, ibn, ib2, cfa, wg, bg, abn, angp,
                                B1, B2, node_out, E);
  k_mrg<<<tb, 256, 0, stream>>>(node_out, el, src, dst,
                                mb1, mg, mbn, mb2, B3, B4, edge_out, E);
}

// Round 7
// 1020.431 us; speedup vs baseline: 2.8624x; 1.1474x over previous
//
#include <hip/hip_runtime.h>
#include <math.h>

// Round 8: LDS-staged weight pipeline (2-phase stage/compute/barrier).
// R6 post-mortem: 58% all-wave stall; compiler collapsed reg dbuf (VGPR 84).
// Weights now flow global->reg (issued a full step early) -> ds_write ->
// barrier -> ds_read feeding MFMA. One stage per block (was 4x per-wave VMEM).
// k_inv: half-nt 6-frag stages dbuf'd (12.3KB LDS); k_mrg: full-nt 10-frag.
// Numerics identical to R6-pass (same data, same MFMA order).

typedef short short8 __attribute__((ext_vector_type(8)));
typedef float f32x4 __attribute__((ext_vector_type(4)));

#define SFA 392   // k_inv feat row stride (ushorts); 784B -> 2-way bank alias (free)
#define SFB 328   // k_mrg feat row stride (ushorts)

__device__ __forceinline__ unsigned short f2bf(float x) {
  union { float f; unsigned u; } v; v.f = x;
  unsigned r = (v.u + 0x7FFFu + ((v.u >> 16) & 1u)) >> 16;
  return (unsigned short)r;
}
__device__ __forceinline__ float bf2f(unsigned short h) {
  union { unsigned u; float f; } v; v.u = ((unsigned)h) << 16;
  return v.f;
}
__device__ __forceinline__ float silu_f(float x) { return x / (1.0f + __expf(-x)); }

__global__ void k_init(float* __restrict__ node_out, int n, int* __restrict__ last_idx) {
  int i = blockIdx.x * blockDim.x + threadIdx.x;
  if (i == 0) *last_idx = -1;
  for (; i < n; i += gridDim.x * blockDim.x) node_out[i] = 0.0f;
}

__global__ void k_mask(const int* __restrict__ src, const int* __restrict__ dst,
                       int E, unsigned char* __restrict__ rawmask, int* __restrict__ last_idx) {
  int i = blockIdx.x * blockDim.x + threadIdx.x;
  if (i >= E) return;
  int s0 = src[i], d0 = dst[i];
  int s1 = (i + 1 < E) ? src[i + 1] : 0;   // _shift pads 0
  int d1 = (i + 1 < E) ? dst[i + 1] : 0;
  int m = (s0 == s1) && (s0 != d0) && (s1 != d1);
  rawmask[i] = (unsigned char)m;
  if (m) atomicMax(last_idx, i);
}

// Wfa = iw1[:,320:]@aw2 ; cfa = iw1[:,320:]@ab2 ; angle closed-form LN folds.
__global__ void k_setup(const float* __restrict__ iw1, const float* __restrict__ aw2,
                        const float* __restrict__ ab2,
                        const float* __restrict__ aw1, const float* __restrict__ ab1,
                        const float* __restrict__ ag,
                        float* __restrict__ Wfa, float* __restrict__ cfa,
                        float* __restrict__ wg, float* __restrict__ bg,
                        float* __restrict__ angp) {
  int n = blockIdx.x * blockDim.x + threadIdx.x;
  if (n < 384 * 64) {
    int r = n >> 6, j = n & 63;
    float acc = 0.0f;
    for (int k = 0; k < 64; ++k) acc += iw1[r * 384 + 320 + k] * aw2[k * 64 + j];
    Wfa[n] = acc;
  } else if (n < 384 * 64 + 384) {
    int r = n - 384 * 64;
    float acc = 0.0f;
    for (int k = 0; k < 64; ++k) acc += iw1[r * 384 + 320 + k] * ab2[k];
    cfa[r] = acc;
  } else if (n < 384 * 64 + 384 + 64) {
    int j = n - (384 * 64 + 384);
    float wm = 0.f, bm = 0.f;
    for (int k = 0; k < 64; ++k) { wm += aw1[k]; bm += ab1[k]; }
    wm *= (1.f / 64.f); bm *= (1.f / 64.f);
    wg[j] = (aw1[j] - wm) * ag[j];
    bg[j] = (ab1[j] - bm) * ag[j];
    if (j == 0) {
      float vw = 0.f, cwb = 0.f, vb = 0.f;
      for (int k = 0; k < 64; ++k) {
        float dw = aw1[k] - wm, db = ab1[k] - bm;
        vw += dw * dw; cwb += dw * db; vb += db * db;
      }
      angp[0] = vw * (1.f / 64.f);
      angp[1] = cwb * (1.f / 64.f);
      angp[2] = vb * (1.f / 64.f);
    }
  }
}

// Swizzle weights into B-fragment order: B[(nt*KT+kt)*64 + lane][8] with
// value = W[n = nt*16 + (lane&15)][k = kt*32 + ((lane>>4)&3)*8 + j]  (bf16).
__global__ void k_swz(const float* __restrict__ iw1, const float* __restrict__ iw2,
                      const float* __restrict__ mw1, const float* __restrict__ mw2,
                      const float* __restrict__ Wfa,
                      unsigned short* __restrict__ B1, unsigned short* __restrict__ B2,
                      unsigned short* __restrict__ B3, unsigned short* __restrict__ B4) {
  const int NC1 = 24 * 12 * 64, NC2 = 8 * 12 * 64, NC3 = 8 * 10 * 64, NC4 = 8 * 4 * 64;
  int cid = blockIdx.x * blockDim.x + threadIdx.x;
  int region, rel, KT;
  unsigned short* out;
  if (cid < NC1)                    { region = 1; rel = cid;                KT = 12; out = B1; }
  else if (cid < NC1 + NC2)         { region = 2; rel = cid - NC1;          KT = 12; out = B2; }
  else if (cid < NC1 + NC2 + NC3)   { region = 3; rel = cid - NC1 - NC2;    KT = 10; out = B3; }
  else if (cid < NC1 + NC2 + NC3 + NC4) { region = 4; rel = cid - NC1 - NC2 - NC3; KT = 4; out = B4; }
  else return;
  int l = rel & 63;
  int ktn = rel >> 6;
  int kt = ktn % KT, nt = ktn / KT;
  int n = nt * 16 + (l & 15);
  int k0 = kt * 32 + ((l >> 4) & 3) * 8;
  short8 pk;
  #pragma unroll
  for (int j = 0; j < 8; ++j) {
    int k = k0 + j;
    float v;
    if (region == 1)      v = (k < 320) ? iw1[n * 384 + k] : Wfa[n * 64 + (k - 320)];
    else if (region == 2) v = iw2[n * 384 + k];
    else if (region == 3) v = mw1[n * 320 + k];
    else                  v = mw2[n * 128 + k];
    pk[j] = (short)f2bf(v);
  }
  *(short8*)(out + ((size_t)rel << 3)) = pk;
}

__global__ __launch_bounds__(256, 2)
void k_inv(const float* __restrict__ atom, const float* __restrict__ el,
           const float* __restrict__ ev,
           const int* __restrict__ src, const int* __restrict__ dst,
           const unsigned char* __restrict__ rawmask, const int* __restrict__ last_idx,
           const float* __restrict__ ib1, const float* __restrict__ ig,
           const float* __restrict__ ibn, const float* __restrict__ ib2,
           const float* __restrict__ cfa, const float* __restrict__ wg,
           const float* __restrict__ bg, const float* __restrict__ abn,
           const float* __restrict__ angp,
           const unsigned short* __restrict__ Bsw1, const unsigned short* __restrict__ Bsw2,
           float* __restrict__ node_out, int E) {
  __shared__ __attribute__((aligned(16))) unsigned short sf[64 * SFA];    // 50176 B
  __shared__ __attribute__((aligned(16))) unsigned short wb0[6 * 512];    // 6144 B
  __shared__ __attribute__((aligned(16))) unsigned short wb1[6 * 512];    // 6144 B
  __shared__ float scos[64], srr[64], smaskf[64], smean[64], srstd[64];
  __shared__ int ssrc[64], sdst[64], sdsts[64];

  const int t = threadIdx.x;
  const int lane = t & 63;
  const int w = t >> 6;
  const int q = (lane >> 4) & 3;
  const int col = lane & 15;
  const int mbase = w * 16;
  const int geb = blockIdx.x * 64;

  // weight stage registers + helpers (wave w owns frags {w, w+4(if w<2)} of 6)
  short8 stgA, stgB;
  auto issue6 = [&](const unsigned short* B, int fb) {
    stgA = *(const short8*)(B + (((size_t)(fb + w) * 64 + lane) << 3));
    if (w < 2) stgB = *(const short8*)(B + (((size_t)(fb + 4 + w) * 64 + lane) << 3));
  };
  auto write6 = [&](unsigned short* wb) {
    *(short8*)(wb + w * 512 + lane * 8) = stgA;
    if (w < 2) *(short8*)(wb + (w + 4) * 512 + lane * 8) = stgB;
  };

  // stage-0 (GEMM1 nt0, kt0-5): issue at top, latency hides under pre-pass+staging
  issue6(Bsw1, 0);

  // ---- pre-pass: per-edge mask, indices, cos, closed-form LN rstd ----
  if (t < 64) {
    int e = t, ge = geb + e;
    int last = *last_idx;
    int ok = ge < E;
    int m0 = 0, m1 = 0, s0 = 0, d0 = 0, d1 = 0;
    if (ok) { s0 = src[ge]; d0 = dst[ge]; m0 = rawmask[ge] && (ge != last); }
    if (ge + 1 < E) { d1 = dst[ge + 1]; m1 = rawmask[ge + 1] && (ge + 1 != last); }
    ssrc[e] = s0; sdst[e] = d0; sdsts[e] = d1;
    smaskf[e] = m0 ? 1.0f : 0.0f;
    float cosv = 0.f;
    if (m0 && m1) {
      float ax = ev[3 * ge], ay = ev[3 * ge + 1], az = ev[3 * ge + 2];
      float bx = ev[3 * ge + 3], by = ev[3 * ge + 4], bz = ev[3 * ge + 5];
      cosv = (ax * bx + ay * by + az * bz) *
             rsqrtf((ax * ax + ay * ay + az * az) * (bx * bx + by * by + bz * bz));
    }
    scos[e] = cosv;
    srr[e] = rsqrtf(cosv * cosv * angp[0] + 2.f * cosv * angp[1] + angp[2] + 1e-6f);
  }
  __syncthreads();

  // ---- stage feat [64][384] bf16 into LDS: 4 threads/edge, division-free ----
  {
    const int es = t >> 2, sub = t & 3;
    const int ge = geb + es;
    const float mk = smaskf[es];
    unsigned short* drw = sf + es * SFA;
    if (mk > 0.f) {
      const float* p0 = atom + (size_t)ssrc[es] * 64 + sub * 8;
      const float* p1 = atom + (size_t)sdst[es] * 64 + sub * 8;
      const float* p2 = el + (size_t)ge * 64 + sub * 8;
      const float* p3 = atom + (size_t)sdsts[es] * 64 + sub * 8;
      const float* p4 = el + (size_t)(ge + 1) * 64 + sub * 8;
      auto stage8 = [&](int colb, const float* sp) {
        float4 a = *(const float4*)sp;
        float4 b = *(const float4*)(sp + 4);
        short8 pk;
        pk[0] = (short)f2bf(a.x); pk[1] = (short)f2bf(a.y);
        pk[2] = (short)f2bf(a.z); pk[3] = (short)f2bf(a.w);
        pk[4] = (short)f2bf(b.x); pk[5] = (short)f2bf(b.y);
        pk[6] = (short)f2bf(b.z); pk[7] = (short)f2bf(b.w);
        *(short8*)(drw + colb) = pk;
      };
      stage8(sub * 8,        p0);  stage8(32 + sub * 8,  p0 + 32);
      stage8(64 + sub * 8,   p1);  stage8(96 + sub * 8,  p1 + 32);
      stage8(128 + sub * 8,  p2);  stage8(160 + sub * 8, p2 + 32);
      stage8(192 + sub * 8,  p3);  stage8(224 + sub * 8, p3 + 32);
      stage8(256 + sub * 8,  p4);  stage8(288 + sub * 8, p4 + 32);
      const float cosv = scos[es], rr = srr[es];
      #pragma unroll
      for (int ii = 0; ii < 2; ++ii) {
        const int j0 = sub * 8 + ii * 32;
        float4 w0 = *(const float4*)(wg + j0),  w1 = *(const float4*)(wg + j0 + 4);
        float4 g0 = *(const float4*)(bg + j0),  g1 = *(const float4*)(bg + j0 + 4);
        float4 n0 = *(const float4*)(abn + j0), n1 = *(const float4*)(abn + j0 + 4);
        short8 pk;
        pk[0] = (short)f2bf(silu_f((cosv * w0.x + g0.x) * rr + n0.x));
        pk[1] = (short)f2bf(silu_f((cosv * w0.y + g0.y) * rr + n0.y));
        pk[2] = (short)f2bf(silu_f((cosv * w0.z + g0.z) * rr + n0.z));
        pk[3] = (short)f2bf(silu_f((cosv * w0.w + g0.w) * rr + n0.w));
        pk[4] = (short)f2bf(silu_f((cosv * w1.x + g1.x) * rr + n1.x));
        pk[5] = (short)f2bf(silu_f((cosv * w1.y + g1.y) * rr + n1.y));
        pk[6] = (short)f2bf(silu_f((cosv * w1.z + g1.z) * rr + n1.z));
        pk[7] = (short)f2bf(silu_f((cosv * w1.w + g1.w) * rr + n1.w));
        *(short8*)(drw + 320 + j0) = pk;
      }
    } else {
      short8 z = {0, 0, 0, 0, 0, 0, 0, 0};
      #pragma unroll
      for (int ii = 0; ii < 12; ++ii)
        *(short8*)(drw + sub * 8 + ii * 32) = z;
    }
  }
  // publish stage-0 weights; barrier drains both feat stores and these
  write6(wb0);
  __syncthreads();

  // ---- per-wave A-fragments (entire feat row slice) + row meta ----
  short8 af[12];
  #pragma unroll
  for (int kt = 0; kt < 12; ++kt)
    af[kt] = *(const short8*)(sf + (mbase + col) * SFA + kt * 32 + q * 8);

  float mrow[4]; int drow[4];
  #pragma unroll
  for (int r = 0; r < 4; ++r) {
    int e = mbase + q * 4 + r;
    mrow[r] = smaskf[e];
    drow[r] = sdst[e];
  }

  // ---- GEMM1: 24 nt x (2 half-steps); weights via LDS 2-phase pipeline ----
  float sums[4] = {0, 0, 0, 0}, sqs[4] = {0, 0, 0, 0};
  float bv = ib1[col], cv = cfa[col];
  #pragma unroll 1
  for (int nt = 0; nt < 24; ++nt) {
    // half 0: consume wb0 (kt 0-5); stage half1 -> wb1
    issue6(Bsw1, nt * 12 + 6);
    f32x4 acc;
    #pragma unroll
    for (int r = 0; r < 4; ++r) acc[r] = bv + mrow[r] * cv;
    #pragma unroll
    for (int kt = 0; kt < 6; ++kt) {
      short8 bw = *(const short8*)(wb0 + kt * 512 + lane * 8);
      acc = __builtin_amdgcn_mfma_f32_16x16x32_bf16(af[kt], bw, acc, 0, 0, 0);
    }
    write6(wb1);
    __syncthreads();
    // half 1: consume wb1 (kt 6-11); stage next half0 -> wb0
    if (nt < 23) issue6(Bsw1, (nt + 1) * 12);
    else         issue6(Bsw2, 0);                 // GEMM2 nt0 kt0-5 prologue
    #pragma unroll
    for (int kt = 0; kt < 6; ++kt) {
      short8 bw = *(const short8*)(wb1 + kt * 512 + lane * 8);
      acc = __builtin_amdgcn_mfma_f32_16x16x32_bf16(af[6 + kt], bw, acc, 0, 0, 0);
    }
    if (nt < 23) { bv = ib1[(nt + 1) * 16 + col]; cv = cfa[(nt + 1) * 16 + col]; }
    #pragma unroll
    for (int r = 0; r < 4; ++r) {
      float vv = acc[r];
      sums[r] += vv; sqs[r] += vv * vv;
      sf[(mbase + q * 4 + r) * SFA + nt * 16 + col] = f2bf(vv);
    }
    write6(wb0);
    __syncthreads();
  }

  // ---- LN stats: intra-quad reduce ----
  #pragma unroll
  for (int r = 0; r < 4; ++r) {
    float s = sums[r], ss = sqs[r];
    for (int m = 1; m < 16; m <<= 1) { s += __shfl_xor(s, m, 64); ss += __shfl_xor(ss, m, 64); }
    sums[r] = s; sqs[r] = ss;
  }
  if (col == 0) {
    #pragma unroll
    for (int r = 0; r < 4; ++r) {
      float mean = sums[r] * (1.f / 384.f);
      float var = sqs[r] * (1.f / 384.f) - mean * mean;
      smean[mbase + q * 4 + r] = mean;
      srstd[mbase + q * 4 + r] = rsqrtf(var + 1e-6f);
    }
  }
  __syncthreads();

  // ---- GEMM2 A'-frags: normalize+silu on load ----
  short8 af2[12];
  {
    int e = mbase + col;
    float mean = smean[e], rstd = srstd[e];
    #pragma unroll
    for (int kt = 0; kt < 12; ++kt) {
      int kb = kt * 32 + q * 8;
      short8 h8 = *(const short8*)(sf + e * SFA + kb);
      float4 g0 = *(const float4*)(ig + kb),  g1 = *(const float4*)(ig + kb + 4);
      float4 b0 = *(const float4*)(ibn + kb), b1v = *(const float4*)(ibn + kb + 4);
      float G[8] = {g0.x, g0.y, g0.z, g0.w, g1.x, g1.y, g1.z, g1.w};
      float B[8] = {b0.x, b0.y, b0.z, b0.w, b1v.x, b1v.y, b1v.z, b1v.w};
      short8 pk;
      #pragma unroll
      for (int j = 0; j < 8; ++j) {
        float h = bf2f((unsigned short)h8[j]);
        float hn = (h - mean) * rstd * G[j] + B[j];
        pk[j] = (short)f2bf(silu_f(hn));
      }
      af2[kt] = pk;
    }
  }

  // ---- GEMM2: 8 nt x (2 half-steps); wb0 already holds nt0 kt0-5 ----
  float bv2 = ib2[col];
  #pragma unroll 1
  for (int nt = 0; nt < 8; ++nt) {
    issue6(Bsw2, nt * 12 + 6);
    f32x4 acc;
    #pragma unroll
    for (int r = 0; r < 4; ++r) acc[r] = bv2;
    #pragma unroll
    for (int kt = 0; kt < 6; ++kt) {
      short8 bw = *(const short8*)(wb0 + kt * 512 + lane * 8);
      acc = __builtin_amdgcn_mfma_f32_16x16x32_bf16(af2[kt], bw, acc, 0, 0, 0);
    }
    write6(wb1);
    __syncthreads();
    if (nt < 7) issue6(Bsw2, (nt + 1) * 12);
    #pragma unroll
    for (int kt = 0; kt < 6; ++kt) {
      short8 bw = *(const short8*)(wb1 + kt * 512 + lane * 8);
      acc = __builtin_amdgcn_mfma_f32_16x16x32_bf16(af2[6 + kt], bw, acc, 0, 0, 0);
    }
    if (nt < 7) bv2 = ib2[(nt + 1) * 16 + col];
    #pragma unroll
    for (int r = 0; r < 4; ++r) {
      int ge = geb + mbase + q * 4 + r;
      if (ge < E) atomicAdd(node_out + (size_t)drow[r] * 128 + (nt * 16 + col), acc[r]);
    }
    if (nt < 7) { write6(wb0); __syncthreads(); }
  }
}

__global__ __launch_bounds__(256, 2)
void k_mrg(const float* __restrict__ node, const float* __restrict__ el,
           const int* __restrict__ src, const int* __restrict__ dst,
           const float* __restrict__ mb1, const float* __restrict__ mg,
           const float* __restrict__ mbn, const float* __restrict__ mb2,
           const unsigned short* __restrict__ Bsw3, const unsigned short* __restrict__ Bsw4,
           float* __restrict__ edge_out, int E) {
  __shared__ __attribute__((aligned(16))) unsigned short sf[64 * SFB];    // 41984 B
  __shared__ __attribute__((aligned(16))) unsigned short wbA[10 * 512];   // 10240 B
  __shared__ __attribute__((aligned(16))) unsigned short wbB[10 * 512];   // 10240 B
  __shared__ float smean[64], srstd[64];
  __shared__ int ssrc[64], sdst[64];

  const int t = threadIdx.x;
  const int lane = t & 63;
  const int w = t >> 6;
  const int q = (lane >> 4) & 3;
  const int col = lane & 15;
  const int mbase = w * 16;
  const int geb = blockIdx.x * 64;

  // wave w owns frags {w, w+4, w+8(if w<2)} of 10 ; {w} of 4
  short8 stgA, stgB, stgC;
  auto issue10 = [&](const unsigned short* B, int fb) {
    stgA = *(const short8*)(B + (((size_t)(fb + w) * 64 + lane) << 3));
    stgB = *(const short8*)(B + (((size_t)(fb + 4 + w) * 64 + lane) << 3));
    if (w < 2) stgC = *(const short8*)(B + (((size_t)(fb + 8 + w) * 64 + lane) << 3));
  };
  auto write10 = [&](unsigned short* wb) {
    *(short8*)(wb + w * 512 + lane * 8) = stgA;
    *(short8*)(wb + (w + 4) * 512 + lane * 8) = stgB;
    if (w < 2) *(short8*)(wb + (w + 8) * 512 + lane * 8) = stgC;
  };
  auto issue4 = [&](const unsigned short* B, int fb) {
    stgA = *(const short8*)(B + (((size_t)(fb + w) * 64 + lane) << 3));
  };
  auto write4 = [&](unsigned short* wb) {
    *(short8*)(wb + w * 512 + lane * 8) = stgA;
  };

  issue10(Bsw3, 0);   // GEMM1 nt0 prologue

  if (t < 64) {
    int ge = geb + t;
    int ok = ge < E;
    ssrc[t] = ok ? src[ge] : 0;
    sdst[t] = ok ? dst[ge] : 0;
  }
  __syncthreads();

  // ---- stage [64][320]: node[src] | node[dst] | el ; 4 threads/edge ----
  {
    const int es = t >> 2, sub = t & 3;
    const int ge = geb + es;
    unsigned short* drw = sf + es * SFB;
    if (ge < E) {
      const float* p0 = node + (size_t)ssrc[es] * 128 + sub * 8;
      const float* p1 = node + (size_t)sdst[es] * 128 + sub * 8;
      const float* p2 = el + (size_t)ge * 64 + sub * 8;
      auto stage8 = [&](int colb, const float* sp) {
        float4 a = *(const float4*)sp;
        float4 b = *(const float4*)(sp + 4);
        short8 pk;
        pk[0] = (short)f2bf(a.x); pk[1] = (short)f2bf(a.y);
        pk[2] = (short)f2bf(a.z); pk[3] = (short)f2bf(a.w);
        pk[4] = (short)f2bf(b.x); pk[5] = (short)f2bf(b.y);
        pk[6] = (short)f2bf(b.z); pk[7] = (short)f2bf(b.w);
        *(short8*)(drw + colb) = pk;
      };
      stage8(sub * 8,        p0);       stage8(32 + sub * 8,  p0 + 32);
      stage8(64 + sub * 8,   p0 + 64);  stage8(96 + sub * 8,  p0 + 96);
      stage8(128 + sub * 8,  p1);       stage8(160 + sub * 8, p1 + 32);
      stage8(192 + sub * 8,  p1 + 64);  stage8(224 + sub * 8, p1 + 96);
      stage8(256 + sub * 8,  p2);       stage8(288 + sub * 8, p2 + 32);
    } else {
      short8 z = {0, 0, 0, 0, 0, 0, 0, 0};
      #pragma unroll
      for (int ii = 0; ii < 10; ++ii)
        *(short8*)(drw + sub * 8 + ii * 32) = z;
    }
  }
  write10(wbA);
  __syncthreads();

  short8 af[10];
  #pragma unroll
  for (int kt = 0; kt < 10; ++kt)
    af[kt] = *(const short8*)(sf + (mbase + col) * SFB + kt * 32 + q * 8);

  // ---- GEMM1: 8 nt, full-nt (10-frag) stages, one barrier per nt ----
  float sums[4] = {0, 0, 0, 0}, sqs[4] = {0, 0, 0, 0};
  float bv = mb1[col];
  #pragma unroll 1
  for (int nt = 0; nt < 8; ++nt) {
    unsigned short* rb = (nt & 1) ? wbB : wbA;
    unsigned short* sb = (nt & 1) ? wbA : wbB;
    if (nt < 7) issue10(Bsw3, (nt + 1) * 10);
    else        issue4(Bsw4, 0);                  // GEMM2 nt0 prologue
    f32x4 acc;
    #pragma unroll
    for (int r = 0; r < 4; ++r) acc[r] = bv;
    #pragma unroll
    for (int kt = 0; kt < 10; ++kt) {
      short8 bw = *(const short8*)(rb + kt * 512 + lane * 8);
      acc = __builtin_amdgcn_mfma_f32_16x16x32_bf16(af[kt], bw, acc, 0, 0, 0);
    }
    if (nt < 7) bv = mb1[(nt + 1) * 16 + col];
    #pragma unroll
    for (int r = 0; r < 4; ++r) {
      float vv = acc[r];
      sums[r] += vv; sqs[r] += vv * vv;
      sf[(mbase + q * 4 + r) * SFB + nt * 16 + col] = f2bf(vv);
    }
    if (nt < 7) write10(sb); else write4(sb);
    __syncthreads();
  }

  #pragma unroll
  for (int r = 0; r < 4; ++r) {
    float s = sums[r], ss = sqs[r];
    for (int m = 1; m < 16; m <<= 1) { s += __shfl_xor(s, m, 64); ss += __shfl_xor(ss, m, 64); }
    sums[r] = s; sqs[r] = ss;
  }
  if (col == 0) {
    #pragma unroll
    for (int r = 0; r < 4; ++r) {
      float mean = sums[r] * (1.f / 128.f);
      float var = sqs[r] * (1.f / 128.f) - mean * mean;
      smean[mbase + q * 4 + r] = mean;
      srstd[mbase + q * 4 + r] = rsqrtf(var + 1e-6f);
    }
  }
  __syncthreads();

  short8 af2[4];
  {
    int e = mbase + col;
    float mean = smean[e], rstd = srstd[e];
    #pragma unroll
    for (int kt = 0; kt < 4; ++kt) {
      int kb = kt * 32 + q * 8;
      short8 h8 = *(const short8*)(sf + e * SFB + kb);
      float4 g0 = *(const float4*)(mg + kb),  g1 = *(const float4*)(mg + kb + 4);
      float4 b0 = *(const float4*)(mbn + kb), b1v = *(const float4*)(mbn + kb + 4);
      float G[8] = {g0.x, g0.y, g0.z, g0.w, g1.x, g1.y, g1.z, g1.w};
      float B[8] = {b0.x, b0.y, b0.z, b0.w, b1v.x, b1v.y, b1v.z, b1v.w};
      short8 pk;
      #pragma unroll
      for (int j = 0; j < 8; ++j) {
        float h = bf2f((unsigned short)h8[j]);
        float hn = (h - mean) * rstd * G[j] + B[j];
        pk[j] = (short)f2bf(silu_f(hn));
      }
      af2[kt] = pk;
    }
  }

  // ---- GEMM2: 8 nt, 4-frag stages; GEMM1 nt7 staged nt0 into wbA ----
  float bv2 = mb2[col];
  #pragma unroll 1
  for (int nt = 0; nt < 8; ++nt) {
    unsigned short* rb = (nt & 1) ? wbB : wbA;
    unsigned short* sb = (nt & 1) ? wbA : wbB;
    if (nt < 7) issue4(Bsw4, (nt + 1) * 4);
    f32x4 acc;
    #pragma unroll
    for (int r = 0; r < 4; ++r) acc[r] = bv2;
    #pragma unroll
    for (int kt = 0; kt < 4; ++kt) {
      short8 bw = *(const short8*)(rb + kt * 512 + lane * 8);
      acc = __builtin_amdgcn_mfma_f32_16x16x32_bf16(af2[kt], bw, acc, 0, 0, 0);
    }
    if (nt < 7) bv2 = mb2[(nt + 1) * 16 + col];
    #pragma unroll
    for (int r = 0; r < 4; ++r) {
      int ge = geb + mbase + q * 4 + r;
      if (ge < E) edge_out[(size_t)ge * 128 + (nt * 16 + col)] = acc[r];
    }
    if (nt < 7) { write4(sb); __syncthreads(); }
  }
}

extern "C" void kernel_launch(void* const* d_in, const int* in_sizes, int n_in,
                              void* d_out, int out_size, void* d_ws, size_t ws_size,
                              hipStream_t stream) {
  const float* atom = (const float*)d_in[0];
  const float* el   = (const float*)d_in[1];
  const float* ev   = (const float*)d_in[2];
  const int*   eidx = (const int*)d_in[3];
  const float* aw1  = (const float*)d_in[4];
  const float* ab1  = (const float*)d_in[5];
  const float* ag   = (const float*)d_in[6];
  const float* abn  = (const float*)d_in[7];
  const float* aw2  = (const float*)d_in[8];
  const float* ab2  = (const float*)d_in[9];
  const float* iw1  = (const float*)d_in[10];
  const float* ib1  = (const float*)d_in[11];
  const float* ig   = (const float*)d_in[12];
  const float* ibn  = (const float*)d_in[13];
  const float* iw2  = (const float*)d_in[14];
  const float* ib2  = (const float*)d_in[15];
  const float* mw1  = (const float*)d_in[16];
  const float* mb1  = (const float*)d_in[17];
  const float* mg   = (const float*)d_in[18];
  const float* mbn  = (const float*)d_in[19];
  const float* mw2  = (const float*)d_in[20];
  const float* mb2  = (const float*)d_in[21];

  const int N = in_sizes[0] / 64;
  const int E = in_sizes[1] / 64;
  const int* src = eidx;
  const int* dst = eidx + E;

  char* ws = (char*)d_ws;
  size_t off = 0;
  int* last_idx = (int*)(ws + off);          off += 256;
  unsigned char* rawmask = (unsigned char*)(ws + off); off += ((size_t)E + 255) & ~(size_t)255;
  float* Wfa  = (float*)(ws + off);          off += (size_t)384 * 64 * 4;
  float* cfa  = (float*)(ws + off);          off += 384 * 4;
  float* wg   = (float*)(ws + off);          off += 256;
  float* bg   = (float*)(ws + off);          off += 256;
  float* angp = (float*)(ws + off);          off += 256;
  unsigned short* B1 = (unsigned short*)(ws + off); off += (size_t)24 * 12 * 64 * 8 * 2;
  unsigned short* B2 = (unsigned short*)(ws + off); off += (size_t)8 * 12 * 64 * 8 * 2;
  unsigned short* B3 = (unsigned short*)(ws + off); off += (size_t)8 * 10 * 64 * 8 * 2;
  unsigned short* B4 = (unsigned short*)(ws + off); off += (size_t)8 * 4 * 64 * 8 * 2;

  float* node_out = (float*)d_out;
  float* edge_out = node_out + (size_t)N * 128;

  const int eb = (E + 255) / 256;
  const int tb = (E + 63) / 64;
  const int swz_n = 24 * 12 * 64 + 8 * 12 * 64 + 8 * 10 * 64 + 8 * 4 * 64;

  k_init<<<2048, 256, 0, stream>>>(node_out, N * 128, last_idx);
  k_mask<<<eb, 256, 0, stream>>>(src, dst, E, rawmask, last_idx);
  k_setup<<<(384 * 64 + 384 + 64 + 255) / 256, 256, 0, stream>>>(
      iw1, aw2, ab2, aw1, ab1, ag, Wfa, cfa, wg, bg, angp);
  k_swz<<<(swz_n + 255) / 256, 256, 0, stream>>>(iw1, iw2, mw1, mw2, Wfa, B1, B2, B3, B4);
  k_inv<<<tb, 256, 0, stream>>>(atom, el, ev, src, dst, rawmask, last_idx,
                                ib1, ig, ibn, ib2, cfa, wg, bg, abn, angp,
                                B1, B2, node_out, E);
  k_mrg<<<tb, 256, 0, stream>>>(node_out, el, src, dst,
                                mb1, mg, mbn, mb2, B3, B4, edge_out, E);
}